// Round 5
// baseline (348.954 us; speedup 1.0000x reference)
//
#include <hip/hip_runtime.h>
#include <cstdint>
#include <cstddef>

typedef float  f32x4  __attribute__((ext_vector_type(4)));
typedef float  f32x16 __attribute__((ext_vector_type(16)));
typedef short  s16x8  __attribute__((ext_vector_type(8)));

#define DEV __device__ __forceinline__

static constexpr int    DHW       = 32768;       // 8*64*64
static constexpr int    NTOK      = 65536;       // B*D*H*W
static constexpr int    KCB       = 4096;        // codebook size
static constexpr int    CHUNK_B   = 18432;       // 16384 gh/gl + 1KB e2 + zero slot + pad
static constexpr size_t OUT_ELEMS = 4194304;     // 2*64*32768
static constexpr float  BIGC      = 512.0f;      // positivity bias for uint-compare
static constexpr float  TAU       = 0.015f;      // near-tie refinement threshold
static constexpr int    FLAG_CAP  = 16384;

static constexpr size_t WS_PREP = 0;             // 64*18432 = 1,179,648
static constexpr size_t WS_RES  = 1179648;       // NQ*65536*8 (1 or 2 MB)

DEV unsigned f2bf(float f) {            // RNE float -> bf16 bits
  unsigned u = __float_as_uint(f);
  return (u + 0x7FFFu + ((u >> 16) & 1u)) >> 16;
}
DEV float bf2f(unsigned h) { return __uint_as_float(h << 16); }
DEV unsigned med3u(unsigned a, unsigned b, unsigned c) {
  unsigned r;
  asm("v_med3_u32 %0, %1, %2, %3" : "=v"(r) : "v"(a), "v"(b), "v"(c));
  return r;
}
DEV void gl_lds16(const void* g, void* l) {   // 64 lanes x 16B, dest = base + lane*16
  __builtin_amdgcn_global_load_lds(
      (const __attribute__((address_space(1))) unsigned int*)g,
      (__attribute__((address_space(3))) unsigned int*)l, 16, 0, 0);
}

// ---------------- Kernel A: pre-conv (t = pre_w@z + pre_b) + embedding prep ----
__global__ __launch_bounds__(256) void k_pre(const float* __restrict__ z,
    const float* __restrict__ emb, const float* __restrict__ pw, const float* __restrict__ pb,
    float* __restrict__ dout, char* __restrict__ ws, size_t off_cnt)
{
  const int blk = blockIdx.x, tid = threadIdx.x;
  if (blk == 0 && tid == 0) *(int*)(ws + off_cnt) = 0;
  if (blk < 256) {
    float* t = dout;
    const int v = blk * 256 + tid;
    const int b = v >> 15, r = v & (DHW - 1);
    const float* zp = z + (size_t)b * 64 * DHW + r;
    float zr[64];
#pragma unroll
    for (int c2 = 0; c2 < 64; ++c2) zr[c2] = zp[(size_t)c2 * DHW];
    for (int c = 0; c < 64; ++c) {          // c uniform -> pre_w row via s_load
      float a = pb[c];
      const float* wr = pw + c * 64;
#pragma unroll
      for (int c2 = 0; c2 < 64; ++c2) a = fmaf(wr[c2], zr[c2], a);
      t[(size_t)c * NTOK + v] = a;          // coalesced across lanes
    }
  } else {
    const int tt = (blk - 256) * 256 + tid;  // 0..16383, 2 units each
#pragma unroll
    for (int uu = 0; uu < 2; ++uu) {
      const int u = tt * 2 + uu;
      const int k = u >> 3, j = u & 7;       // code k, 8-channel group j
      const float* ep = emb + (size_t)k * 64 + j * 8;
      unsigned hw[4], lw[4];
#pragma unroll
      for (int i = 0; i < 4; ++i) {
        float g0 = -2.0f * ep[2 * i], g1 = -2.0f * ep[2 * i + 1];
        unsigned h0 = f2bf(g0); unsigned l0 = f2bf(g0 - bf2f(h0));
        unsigned h1 = f2bf(g1); unsigned l1 = f2bf(g1 - bf2f(h1));
        hw[i] = h0 | (h1 << 16); lw[i] = l0 | (l1 << 16);
      }
      char* base = ws + WS_PREP + (size_t)(k >> 6) * CHUNK_B;
      const int r = k & 63;
      const int swz = (r & 15) << 4;
      char* rowp = base + r * 256;
      *(uint4*)(rowp + ((j * 16) ^ swz))        = make_uint4(hw[0], hw[1], hw[2], hw[3]);
      *(uint4*)(rowp + ((128 + j * 16) ^ swz))  = make_uint4(lw[0], lw[1], lw[2], lw[3]);
      if (j == 0) {
        const float* er = emb + (size_t)k * 64;
        float s = 0.f;
#pragma unroll
        for (int c = 0; c < 64; ++c) s = fmaf(er[c], er[c], s);
        s += BIGC;
        unsigned eh  = f2bf(s);
        float    rs  = s - bf2f(eh);
        unsigned el  = f2bf(rs);
        unsigned el2 = f2bf(rs - bf2f(el));
        *(uint4*)(base + 16384 + r * 16) = make_uint4(eh | (el << 16), el2, 0u, 0u);
        if (r == 0) *(uint4*)(base + 16384 + 1024) = make_uint4(0u, 0u, 0u, 0u);
      }
    }
  }
}

// ---------------- Kernel B: bf16x3 MFMA distance (32x32x16), NQ-way chunk split
// grid = 256*NQ blocks x 512 thr. Block: tokens (bid>>log2NQ)*256..+256,
// chunks (bid&(NQ-1))*NCH..+NCH. e2 folded via one extra MFMA per rowtile.
template <int NQ>
__global__ __launch_bounds__(512, 4) void k_dist(float* __restrict__ dout,
                                                 char* __restrict__ ws)
{
  constexpr int NCH = 64 / NQ;
  constexpr int QSH = (NQ == 4) ? 2 : 1;
  __shared__ __align__(16) char smem[2 * CHUNK_B];
  const float* t = dout;                       // [64][NTOK]
  const int tid = threadIdx.x;
  const int w = tid >> 6, lane = tid & 63;
  const int l31 = lane & 31, khalf = lane >> 5;
  const int gidx = blockIdx.x >> QSH, h = blockIdx.x & (NQ - 1);
  const int tb = gidx * 256 + w * 32;
  const int tok = tb + l31;

  // ---- B-fragments: t[k][tok], k = kt*16 + khalf*8 + i ----
  s16x8 tav[4], tlv[4];
#pragma unroll
  for (int kt = 0; kt < 4; ++kt) {
    const float* tc = t + (size_t)(kt * 16 + khalf * 8) * NTOK + tok;
    float f[8];
#pragma unroll
    for (int i = 0; i < 8; ++i) f[i] = tc[(size_t)i * NTOK];
    union { unsigned u[4]; s16x8 v; } xh, xl;
#pragma unroll
    for (int i = 0; i < 4; ++i) {
      unsigned h0 = f2bf(f[2 * i]),     l0 = f2bf(f[2 * i]     - bf2f(h0));
      unsigned h1 = f2bf(f[2 * i + 1]), l1 = f2bf(f[2 * i + 1] - bf2f(h1));
      xh.u[i] = h0 | (h1 << 16); xl.u[i] = l0 | (l1 << 16);
    }
    tav[kt] = xh.v; tlv[kt] = xl.v;
  }
  s16x8 ones;                                  // B for e2-MFMA: k'=0,1,2 -> 1.0 (khalf 0)
  { union { unsigned u[4]; s16x8 v; } o;
    o.u[0] = khalf ? 0u : 0x3F803F80u;
    o.u[1] = khalf ? 0u : 0x00003F80u;
    o.u[2] = 0u; o.u[3] = 0u; ones = o.v; }

  const char* prep = ws + WS_PREP + (size_t)h * NCH * CHUNK_B;
  const int swz = (l31 & 15) << 4;

  // prologue: stage chunk 0 (linear copy: prep is pre-swizzled)
  {
    const char* src = prep;
    gl_lds16(src + w * 1024 + lane * 16, smem + w * 1024);
    gl_lds16(src + 8192 + w * 1024 + lane * 16, smem + 8192 + w * 1024);
    if (w < 2) gl_lds16(src + 16384 + w * 1024 + lane * 16, smem + 16384 + w * 1024);
  }
  __syncthreads();

  unsigned u1 = 0x7f800000u, u2 = 0x7f800000u;
  int c1 = 0;

  for (int c = 0; c < NCH; ++c) {
    const char* L = smem + (c & 1) * CHUNK_B;
    if (c + 1 < NCH) {                         // issue next-chunk stage early
      const char* src = prep + (size_t)(c + 1) * CHUNK_B;
      char* dst = smem + ((c + 1) & 1) * CHUNK_B;
      gl_lds16(src + w * 1024 + lane * 16, dst + w * 1024);
      gl_lds16(src + 8192 + w * 1024 + lane * 16, dst + 8192 + w * 1024);
      if (w < 2) gl_lds16(src + 16384 + w * 1024 + lane * 16, dst + 16384 + w * 1024);
    }
    f32x16 acc0 = {}, acc1 = {};
    {                                          // e2 seed via MFMA (adds 512+||e||^2)
      const s16x8 e0 = *(const s16x8*)(L + (khalf ? (16384 + 1024) : (16384 + l31 * 16)));
      const s16x8 e1 = *(const s16x8*)(L + (khalf ? (16384 + 1024) : (16384 + (32 + l31) * 16)));
      acc0 = __builtin_amdgcn_mfma_f32_32x32x16_bf16(e0, ones, acc0, 0, 0, 0);
      acc1 = __builtin_amdgcn_mfma_f32_32x32x16_bf16(e1, ones, acc1, 0, 0, 0);
    }
#pragma unroll
    for (int kt = 0; kt < 4; ++kt) {
      const int i0 = (kt * 32 + khalf * 16) ^ swz;
      const s16x8 gh0 = *(const s16x8*)(L + l31 * 256 + i0);
      const s16x8 gl0 = *(const s16x8*)(L + l31 * 256 + (i0 ^ 128));
      const s16x8 gh1 = *(const s16x8*)(L + (32 + l31) * 256 + i0);
      const s16x8 gl1 = *(const s16x8*)(L + (32 + l31) * 256 + (i0 ^ 128));
      acc0 = __builtin_amdgcn_mfma_f32_32x32x16_bf16(gh0, tav[kt], acc0, 0, 0, 0);
      acc0 = __builtin_amdgcn_mfma_f32_32x32x16_bf16(gh0, tlv[kt], acc0, 0, 0, 0);
      acc0 = __builtin_amdgcn_mfma_f32_32x32x16_bf16(gl0, tav[kt], acc0, 0, 0, 0);
      acc1 = __builtin_amdgcn_mfma_f32_32x32x16_bf16(gh1, tav[kt], acc1, 0, 0, 0);
      acc1 = __builtin_amdgcn_mfma_f32_32x32x16_bf16(gh1, tlv[kt], acc1, 0, 0, 0);
      acc1 = __builtin_amdgcn_mfma_f32_32x32x16_bf16(gl1, tav[kt], acc1, 0, 0, 0);
    }
    // argmin: C row = rt*32 + (q&3) + 8*(q>>2) + 4*khalf; embed wid (khalf-bit at end)
    const unsigned p1 = u1;
#pragma unroll
    for (int q = 0; q < 16; ++q) {
      const unsigned w0 = (unsigned)((q & 3) + 8 * (q >> 2));
      unsigned v0 = (__float_as_uint(acc0[q]) & ~63u) | w0;
      u2 = med3u(u1, v0, u2); u1 = u1 < v0 ? u1 : v0;
      unsigned v1 = (__float_as_uint(acc1[q]) & ~63u) | (w0 + 32u);
      u2 = med3u(u1, v1, u2); u1 = u1 < v1 ? u1 : v1;
    }
    if (u1 != p1) c1 = c;
    __syncthreads();                           // drains vmcnt -> next chunk staged
  }

  u1 |= (unsigned)(khalf * 4);                 // complete wid (bit 2)
  // merge lane <-> lane+32 (same token, different code rows)
  const unsigned o1 = __shfl_xor(u1, 32);
  const unsigned o2 = __shfl_xor(u2, 32);
  const int      oc = __shfl_xor(c1, 32);
  const unsigned am = u1 & ~63u, om = o1 & ~63u;
  const int mycode = c1 * 64 + (int)(u1 & 63u);
  const int ocode  = oc * 64 + (int)(o1 & 63u);
  const bool owins = (om < am) || (om == am && ocode < mycode);
  const unsigned f1 = owins ? o1 : u1;
  const int      fc = owins ? oc : c1;
  const unsigned mx = owins ? am : om;
  unsigned s2 = (u2 & ~63u) < (o2 & ~63u) ? (u2 & ~63u) : (o2 & ~63u);
  s2 = s2 < mx ? s2 : mx;
  if (khalf == 0) {
    uint2* res = (uint2*)(ws + WS_RES);
    res[h * 65536 + tok] = make_uint2(f1, s2 | (unsigned)fc);
  }
}

// ---------------- Kernel M: merge NQ quarter-results + flags + loss partials ---
template <int NQ>
__global__ __launch_bounds__(256) void k_merge(const float* __restrict__ emb,
    float* __restrict__ dout, char* __restrict__ ws,
    size_t off_idx, size_t off_part, size_t off_cnt, size_t off_flag)
{
  __shared__ float ls[4];
  const int v = blockIdx.x * 256 + threadIdx.x;
  const uint2* res = (const uint2*)(ws + WS_RES);
  unsigned f1 = 0xffffffffu, smin = 0xffffffffu, mlosers = 0xffffffffu;
  int code = 0;
#pragma unroll
  for (int q = 0; q < NQ; ++q) {
    const uint2 R = res[q * 65536 + v];
    const unsigned m = R.x & ~63u;
    const int cd = q * (4096 / NQ) + (int)(R.y & 63u) * 64 + (int)(R.x & 63u);
    const unsigned s2m = R.y & ~63u;
    smin = s2m < smin ? s2m : smin;
    if (m < f1) { mlosers = f1 < mlosers ? f1 : mlosers; f1 = m; code = cd; }
    else        { mlosers = m  < mlosers ? m  : mlosers; }
  }
  const unsigned f2 = smin < mlosers ? smin : mlosers;
  ((int*)(ws + off_idx))[v] = code;
  dout[OUT_ELEMS + 2 + v] = (float)code;
  if (__uint_as_float(f2) - __uint_as_float(f1) < TAU) {
    int p = atomicAdd((int*)(ws + off_cnt), 1);
    if (p < FLAG_CAP) ((int*)(ws + off_flag))[p] = v;
  }
  // loss: sum (t - q)^2 for this token
  const float* tcol = dout + v;                // t[c][v]
  const float* q = emb + (size_t)code * 64;
  float acc = 0.f;
#pragma unroll
  for (int cch = 0; cch < 64; ++cch) {
    const float d = tcol[(size_t)cch * NTOK] - q[cch];
    acc = fmaf(d, d, acc);
  }
#pragma unroll
  for (int m = 1; m < 64; m <<= 1) acc += __shfl_xor(acc, m);
  const int lane = threadIdx.x & 63, wv = threadIdx.x >> 6;
  if (lane == 0) ls[wv] = acc;
  __syncthreads();
  if (threadIdx.x == 0)
    ((float*)(ws + off_part))[blockIdx.x] = ls[0] + ls[1] + ls[2] + ls[3];
}

// ---------------- Kernel R: f64 re-scan of near-tie tokens --------------------
// 16 tokens/block (16 waves, 1024 thr) sharing double-buffered swizzled LDS
// codebook tiles -> emb traffic / 16 per token vs wave-private. Scalar dmin/kmin.
__global__ __launch_bounds__(1024) void k_refine(const float* __restrict__ z,
    const float* __restrict__ emb, const float* __restrict__ pw, const float* __restrict__ pb,
    float* __restrict__ dout, char* __restrict__ ws,
    size_t off_idx, size_t off_cnt, size_t off_flag)
{
  __shared__ __align__(16) float etile[2][4096];   // 2 x 16KB swizzled code tiles
  __shared__ double tdsh[16][64];                  // per-wave token t (f64)
  int cv = *(const int*)(ws + off_cnt);
  if (cv > FLAG_CAP) cv = FLAG_CAP;
  const int base = blockIdx.x * 16;
  if (base >= cv) return;
  const int tid = threadIdx.x;
  const int w = tid >> 6, lane = tid & 63;
  const int slot = base + w;
  const bool active = slot < cv;
  const int n = active ? ((const int*)(ws + off_flag))[slot] : 0;

  if (active) {                                    // recompute token t in f64
    const int b = n >> 15, r = n & (DHW - 1);
    const float* zp = z + (size_t)b * 64 * DHW + r;
    const float* wr = pw + lane * 64;
    double a = (double)pb[lane];
    for (int c2 = 0; c2 < 64; ++c2)
      a = fma((double)wr[c2], (double)zp[(size_t)c2 * DHW], a);
    tdsh[w][lane] = a;
  }
  __syncthreads();
  const int s = lane >> 4, lo = lane & 15;
  double tdv[16];                                  // channels s*16 .. s*16+15
#pragma unroll
  for (int j = 0; j < 16; ++j) tdv[j] = tdsh[w][s * 16 + j];

  // stage tile 0: unit u = tid -> code c=u>>4, granule g=u&15,
  // swizzled byte = c*256 + ((g*16) ^ ((c&15)<<4))  (conflict-free both sides)
  const float4* esrc = (const float4*)emb;
  float4 rg = esrc[tid];
  {
    char* bp = (char*)etile[0];
    const int c = tid >> 4, g = tid & 15;
    *(float4*)(bp + c * 256 + ((g * 16) ^ ((c & 15) << 4))) = rg;
  }
  __syncthreads();

  const int ebase0 = lo * 256 + ((s << 6) ^ (lo << 4));
  double dmin = 1e300; int kmin = 0;

  for (int t = 0; t < 64; ++t) {
    if (t < 63) rg = esrc[(t + 1) * 1024 + tid];   // issue next-tile load early
    if (active) {
      const char* buf = (const char*)etile[t & 1];
#pragma unroll
      for (int p = 0; p < 4; ++p) {
        const char* bp = buf + p * 4096;
        const float4 e0 = *(const float4*)(bp + (ebase0 ^ 0));
        const float4 e1 = *(const float4*)(bp + (ebase0 ^ 16));
        const float4 e2 = *(const float4*)(bp + (ebase0 ^ 32));
        const float4 e3 = *(const float4*)(bp + (ebase0 ^ 48));
        double d0 = 0.0, d1 = 0.0;
#define ACC4(E, J) { \
        const double x0 = tdv[J]     - (double)E.x; d0 = fma(x0, x0, d0); \
        const double x1 = tdv[J + 1] - (double)E.y; d1 = fma(x1, x1, d1); \
        const double x2 = tdv[J + 2] - (double)E.z; d0 = fma(x2, x2, d0); \
        const double x3 = tdv[J + 3] - (double)E.w; d1 = fma(x3, x3, d1); }
        ACC4(e0, 0) ACC4(e1, 4) ACC4(e2, 8) ACC4(e3, 12)
#undef ACC4
        double dsum = d0 + d1;
        dsum += __shfl_xor(dsum, 16);              // IEEE add commutative -> quad-identical
        dsum += __shfl_xor(dsum, 32);
        const int code = t * 64 + p * 16 + lo;     // ascending -> strict < keeps first
        if (dsum < dmin) { dmin = dsum; kmin = code; }
      }
    }
    __syncthreads();                               // readers done with buf[(t+1)&1]
    if (t < 63) {
      char* bp = (char*)etile[(t + 1) & 1];
      const int c = tid >> 4, g = tid & 15;
      *(float4*)(bp + c * 256 + ((g * 16) ^ ((c & 15) << 4))) = rg;
    }
    __syncthreads();                               // writes visible for next tile
  }

  // merge the 16 per-lane code classes (s-groups are redundant duplicates)
#pragma unroll
  for (int m = 1; m < 16; m <<= 1) {
    const double od = __shfl_xor(dmin, m);
    const int    ok = __shfl_xor(kmin, m);
    if (od < dmin || (od == dmin && ok < kmin)) { dmin = od; kmin = ok; }
  }
  if (active && lane == 0) {
    ((int*)(ws + off_idx))[n] = kmin;
    dout[OUT_ELEMS + 2 + n] = (float)kmin;
  }
}

// ---------------- Kernel D: post-conv (out = post_w@q + post_b) + loss final ---
__global__ __launch_bounds__(256) void k_post(const float* __restrict__ emb,
    const float* __restrict__ ow, const float* __restrict__ ob,
    float* __restrict__ dout, const char* __restrict__ ws,
    size_t off_idx, size_t off_part)
{
  __shared__ float ps[256];
  const int v = blockIdx.x * 256 + threadIdx.x;
  const int b = v >> 15, r = v & (DHW - 1);
  const int code = ((const int*)(ws + off_idx))[v];
  const float* q = emb + (size_t)code * 64;
  float qr[64];
#pragma unroll
  for (int i = 0; i < 64; ++i) qr[i] = q[i];
  float* op = dout + (size_t)b * 64 * DHW + r;
  for (int o = 0; o < 64; ++o) {              // o uniform -> post_w row via s_load
    float a = ob[o];
    const float* wr = ow + o * 64;
#pragma unroll
    for (int cch = 0; cch < 64; ++cch) a = fmaf(wr[cch], qr[cch], a);
    op[(size_t)o * DHW] = a;                  // coalesced
  }
  if (blockIdx.x == 0) {
    ps[threadIdx.x] = ((const float*)(ws + off_part))[threadIdx.x];
    __syncthreads();
    if (threadIdx.x == 0) {
      float s = 0.f;
      for (int i = 0; i < 256; ++i) s += ps[i];   // fixed order: deterministic
      const float mean = s / 4194304.0f;
      dout[OUT_ELEMS]     = mean;   // codebook_loss
      dout[OUT_ELEMS + 1] = mean;   // commitment_loss
    }
  }
}

extern "C" void kernel_launch(void* const* d_in, const int* in_sizes, int n_in,
                              void* d_out, int out_size, void* d_ws, size_t ws_size,
                              hipStream_t stream) {
  (void)in_sizes; (void)n_in; (void)out_size;
  const float* z   = (const float*)d_in[0];
  const float* emb = (const float*)d_in[1];
  const float* pw  = (const float*)d_in[2];
  const float* pb  = (const float*)d_in[3];
  const float* ow  = (const float*)d_in[4];
  const float* ob  = (const float*)d_in[5];
  float* out = (float*)d_out;
  char*  ws  = (char*)d_ws;

  // ws layout depends on chunk-split NQ (res = NQ MB/2); fall back if ws is small
  const int NQ = (ws_size >= 3700000) ? 4 : 2;
  const size_t off_idx  = WS_RES + (size_t)NQ * 65536 * 8;
  const size_t off_part = off_idx + 262144;
  const size_t off_cnt  = off_part + 1024;
  const size_t off_flag = off_cnt + 256;

  k_pre<<<dim3(320), dim3(256), 0, stream>>>(z, emb, pw, pb, out, ws, off_cnt);
  if (NQ == 4) {
    k_dist<4><<<dim3(1024), dim3(512), 0, stream>>>(out, ws);
    k_merge<4><<<dim3(256), dim3(256), 0, stream>>>(emb, out, ws, off_idx, off_part, off_cnt, off_flag);
  } else {
    k_dist<2><<<dim3(512), dim3(512), 0, stream>>>(out, ws);
    k_merge<2><<<dim3(256), dim3(256), 0, stream>>>(emb, out, ws, off_idx, off_part, off_cnt, off_flag);
  }
  k_refine<<<dim3(FLAG_CAP / 16), dim3(1024), 0, stream>>>(z, emb, pw, pb, out, ws, off_idx, off_cnt, off_flag);
  k_post<<<dim3(256), dim3(256), 0, stream>>>(emb, ow, ob, out, ws, off_idx, off_part);
}

// Round 6
// 327.114 us; speedup vs baseline: 1.0668x; 1.0668x over previous
//
#include <hip/hip_runtime.h>
#include <cstdint>
#include <cstddef>

typedef float  f32x4  __attribute__((ext_vector_type(4)));
typedef float  f32x16 __attribute__((ext_vector_type(16)));
typedef short  s16x8  __attribute__((ext_vector_type(8)));

#define DEV __device__ __forceinline__

static constexpr int    DHW       = 32768;       // 8*64*64
static constexpr int    NTOK      = 65536;       // B*D*H*W
static constexpr int    CHUNK_B   = 18432;       // 16384 gh/gl + 1KB e2 + zero slot + pad
static constexpr size_t OUT_ELEMS = 4194304;     // 2*64*32768
static constexpr float  BIGC      = 512.0f;      // positivity bias for uint-compare
static constexpr float  TAU       = 0.015f;      // near-tie refinement threshold
static constexpr int    FLAG_CAP  = 8192;

// workspace layout (end = 2,524,416 B — identical to the round-1-proven footprint)
static constexpr size_t WS_PREP = 0;             // 64*18432 = 1,179,648
static constexpr size_t WS_RESW = 1179648;       // 4*65536*4 = 1,048,576 (per-quarter winner word)
static constexpr size_t WS_RESB = 2228224;       // 4*65536*1 = 262,144  (chunk | tie-bit)
static constexpr size_t WS_PART = 2490368;       // 256*4
static constexpr size_t WS_CNT  = 2491392;       // int
static constexpr size_t WS_FLAG = 2491648;       // FLAG_CAP*4 -> end 2,524,416

DEV unsigned f2bf(float f) {            // RNE float -> bf16 bits
  unsigned u = __float_as_uint(f);
  return (u + 0x7FFFu + ((u >> 16) & 1u)) >> 16;
}
DEV float bf2f(unsigned h) { return __uint_as_float(h << 16); }
DEV unsigned med3u(unsigned a, unsigned b, unsigned c) {
  unsigned r;
  asm("v_med3_u32 %0, %1, %2, %3" : "=v"(r) : "v"(a), "v"(b), "v"(c));
  return r;
}
DEV void gl_lds16(const void* g, void* l) {   // 64 lanes x 16B, dest = base + lane*16
  __builtin_amdgcn_global_load_lds(
      (const __attribute__((address_space(1))) unsigned int*)g,
      (__attribute__((address_space(3))) unsigned int*)l, 16, 0, 0);
}

// ---------------- Kernel A: pre-conv (t = pre_w@z + pre_b) + embedding prep ----
// t stored [C=64][NTOK] inside d_out (overwritten later by k_post).
__global__ __launch_bounds__(256) void k_pre(const float* __restrict__ z,
    const float* __restrict__ emb, const float* __restrict__ pw, const float* __restrict__ pb,
    float* __restrict__ dout, char* __restrict__ ws)
{
  const int blk = blockIdx.x, tid = threadIdx.x;
  if (blk == 0 && tid == 0) *(int*)(ws + WS_CNT) = 0;
  if (blk < 256) {
    float* t = dout;
    const int v = blk * 256 + tid;
    const int b = v >> 15, r = v & (DHW - 1);
    const float* zp = z + (size_t)b * 64 * DHW + r;
    float zr[64];
#pragma unroll
    for (int c2 = 0; c2 < 64; ++c2) zr[c2] = zp[(size_t)c2 * DHW];
    for (int c = 0; c < 64; ++c) {          // c uniform -> pre_w row via s_load
      float a = pb[c];
      const float* wr = pw + c * 64;
#pragma unroll
      for (int c2 = 0; c2 < 64; ++c2) a = fmaf(wr[c2], zr[c2], a);
      t[(size_t)c * NTOK + v] = a;          // coalesced across lanes
    }
  } else {
    const int tt = (blk - 256) * 256 + tid;  // 0..16383, 2 units each
#pragma unroll
    for (int uu = 0; uu < 2; ++uu) {
      const int u = tt * 2 + uu;
      const int k = u >> 3, j = u & 7;       // code k, 8-channel group j
      const float* ep = emb + (size_t)k * 64 + j * 8;
      unsigned hw[4], lw[4];
#pragma unroll
      for (int i = 0; i < 4; ++i) {
        float g0 = -2.0f * ep[2 * i], g1 = -2.0f * ep[2 * i + 1];
        unsigned h0 = f2bf(g0); unsigned l0 = f2bf(g0 - bf2f(h0));
        unsigned h1 = f2bf(g1); unsigned l1 = f2bf(g1 - bf2f(h1));
        hw[i] = h0 | (h1 << 16); lw[i] = l0 | (l1 << 16);
      }
      char* base = ws + WS_PREP + (size_t)(k >> 6) * CHUNK_B;
      const int r = k & 63;
      const int swz = (r & 15) << 4;
      char* rowp = base + r * 256;
      *(uint4*)(rowp + ((j * 16) ^ swz))        = make_uint4(hw[0], hw[1], hw[2], hw[3]);
      *(uint4*)(rowp + ((128 + j * 16) ^ swz))  = make_uint4(lw[0], lw[1], lw[2], lw[3]);
      if (j == 0) {
        const float* er = emb + (size_t)k * 64;
        float s = 0.f;
#pragma unroll
        for (int c = 0; c < 64; ++c) s = fmaf(er[c], er[c], s);
        s += BIGC;
        unsigned eh  = f2bf(s);
        float    rs  = s - bf2f(eh);
        unsigned el  = f2bf(rs);
        unsigned el2 = f2bf(rs - bf2f(el));
        *(uint4*)(base + 16384 + r * 16) = make_uint4(eh | (el << 16), el2, 0u, 0u);
        if (r == 0) *(uint4*)(base + 16384 + 1024) = make_uint4(0u, 0u, 0u, 0u);
      }
    }
  }
}

// ---------------- Kernel B: bf16x3 MFMA distance (32x32x16), 4-way chunk split -
// grid = 1024 blocks x 512 thr. Block: tokens (bid>>2)*256..+256,
// chunks (bid&3)*16..+16. e2 folded via one extra MFMA per rowtile.
__global__ __launch_bounds__(512, 4) void k_dist(float* __restrict__ dout,
                                                 char* __restrict__ ws)
{
  constexpr int NCH = 16;
  __shared__ __align__(16) char smem[2 * CHUNK_B];
  const float* t = dout;                       // [64][NTOK]
  const int tid = threadIdx.x;
  const int w = tid >> 6, lane = tid & 63;
  const int l31 = lane & 31, khalf = lane >> 5;
  const int gidx = blockIdx.x >> 2, h = blockIdx.x & 3;
  const int tb = gidx * 256 + w * 32;
  const int tok = tb + l31;

  // ---- B-fragments: t[k][tok], k = kt*16 + khalf*8 + i ----
  s16x8 tav[4], tlv[4];
#pragma unroll
  for (int kt = 0; kt < 4; ++kt) {
    const float* tc = t + (size_t)(kt * 16 + khalf * 8) * NTOK + tok;
    float f[8];
#pragma unroll
    for (int i = 0; i < 8; ++i) f[i] = tc[(size_t)i * NTOK];
    union { unsigned u[4]; s16x8 v; } xh, xl;
#pragma unroll
    for (int i = 0; i < 4; ++i) {
      unsigned h0 = f2bf(f[2 * i]),     l0 = f2bf(f[2 * i]     - bf2f(h0));
      unsigned h1 = f2bf(f[2 * i + 1]), l1 = f2bf(f[2 * i + 1] - bf2f(h1));
      xh.u[i] = h0 | (h1 << 16); xl.u[i] = l0 | (l1 << 16);
    }
    tav[kt] = xh.v; tlv[kt] = xl.v;
  }
  s16x8 ones;                                  // B for e2-MFMA: k'=0,1,2 -> 1.0 (khalf 0)
  { union { unsigned u[4]; s16x8 v; } o;
    o.u[0] = khalf ? 0u : 0x3F803F80u;
    o.u[1] = khalf ? 0u : 0x00003F80u;
    o.u[2] = 0u; o.u[3] = 0u; ones = o.v; }

  const char* prep = ws + WS_PREP + (size_t)h * NCH * CHUNK_B;
  const int swz = (l31 & 15) << 4;

  // prologue: stage chunk 0 (linear copy: prep is pre-swizzled)
  {
    const char* src = prep;
    gl_lds16(src + w * 1024 + lane * 16, smem + w * 1024);
    gl_lds16(src + 8192 + w * 1024 + lane * 16, smem + 8192 + w * 1024);
    if (w < 2) gl_lds16(src + 16384 + w * 1024 + lane * 16, smem + 16384 + w * 1024);
  }
  __syncthreads();

  unsigned u1 = 0x7f800000u, u2 = 0x7f800000u;
  int c1 = 0;

  for (int c = 0; c < NCH; ++c) {
    const char* L = smem + (c & 1) * CHUNK_B;
    if (c + 1 < NCH) {                         // issue next-chunk stage early
      const char* src = prep + (size_t)(c + 1) * CHUNK_B;
      char* dst = smem + ((c + 1) & 1) * CHUNK_B;
      gl_lds16(src + w * 1024 + lane * 16, dst + w * 1024);
      gl_lds16(src + 8192 + w * 1024 + lane * 16, dst + 8192 + w * 1024);
      if (w < 2) gl_lds16(src + 16384 + w * 1024 + lane * 16, dst + 16384 + w * 1024);
    }
    f32x16 acc0 = {}, acc1 = {};
    {                                          // e2 seed via MFMA (adds 512+||e||^2)
      const s16x8 e0 = *(const s16x8*)(L + (khalf ? (16384 + 1024) : (16384 + l31 * 16)));
      const s16x8 e1 = *(const s16x8*)(L + (khalf ? (16384 + 1024) : (16384 + (32 + l31) * 16)));
      acc0 = __builtin_amdgcn_mfma_f32_32x32x16_bf16(e0, ones, acc0, 0, 0, 0);
      acc1 = __builtin_amdgcn_mfma_f32_32x32x16_bf16(e1, ones, acc1, 0, 0, 0);
    }
#pragma unroll
    for (int kt = 0; kt < 4; ++kt) {
      const int i0 = (kt * 32 + khalf * 16) ^ swz;
      const s16x8 gh0 = *(const s16x8*)(L + l31 * 256 + i0);
      const s16x8 gl0 = *(const s16x8*)(L + l31 * 256 + (i0 ^ 128));
      const s16x8 gh1 = *(const s16x8*)(L + (32 + l31) * 256 + i0);
      const s16x8 gl1 = *(const s16x8*)(L + (32 + l31) * 256 + (i0 ^ 128));
      acc0 = __builtin_amdgcn_mfma_f32_32x32x16_bf16(gh0, tav[kt], acc0, 0, 0, 0);
      acc0 = __builtin_amdgcn_mfma_f32_32x32x16_bf16(gh0, tlv[kt], acc0, 0, 0, 0);
      acc0 = __builtin_amdgcn_mfma_f32_32x32x16_bf16(gl0, tav[kt], acc0, 0, 0, 0);
      acc1 = __builtin_amdgcn_mfma_f32_32x32x16_bf16(gh1, tav[kt], acc1, 0, 0, 0);
      acc1 = __builtin_amdgcn_mfma_f32_32x32x16_bf16(gh1, tlv[kt], acc1, 0, 0, 0);
      acc1 = __builtin_amdgcn_mfma_f32_32x32x16_bf16(gl1, tav[kt], acc1, 0, 0, 0);
    }
    // argmin: C row = rt*32 + (q&3) + 8*(q>>2) + 4*khalf; khalf bit |'d at end
    const unsigned p1 = u1;
#pragma unroll
    for (int q = 0; q < 16; ++q) {
      const unsigned w0 = (unsigned)((q & 3) + 8 * (q >> 2));
      unsigned v0 = (__float_as_uint(acc0[q]) & ~63u) | w0;
      u2 = med3u(u1, v0, u2); u1 = u1 < v0 ? u1 : v0;
      unsigned v1 = (__float_as_uint(acc1[q]) & ~63u) | (w0 + 32u);
      u2 = med3u(u1, v1, u2); u1 = u1 < v1 ? u1 : v1;
    }
    if (u1 != p1) c1 = c;
    __syncthreads();                           // drains vmcnt -> next chunk staged
  }

  u1 |= (unsigned)(khalf * 4);                 // complete wid (bit 2)
  // merge lane <-> lane+32 (same token, different code rows)
  const unsigned o1 = __shfl_xor(u1, 32);
  const unsigned o2 = __shfl_xor(u2, 32);
  const int      oc = __shfl_xor(c1, 32);
  const unsigned am = u1 & ~63u, om = o1 & ~63u;
  const int mycode = c1 * 64 + (int)(u1 & 63u);
  const int ocode  = oc * 64 + (int)(o1 & 63u);
  const bool owins = (om < am) || (om == am && ocode < mycode);
  const unsigned f1 = owins ? o1 : u1;
  const int      fc = owins ? oc : c1;
  const unsigned mx = owins ? am : om;
  unsigned s2 = (u2 & ~63u) < (o2 & ~63u) ? (u2 & ~63u) : (o2 & ~63u);
  s2 = s2 < mx ? s2 : mx;
  if (khalf == 0) {
    const bool nt = (__uint_as_float(s2) - __uint_as_float(f1 & ~63u)) < TAU;
    ((unsigned*)(ws + WS_RESW))[h * 65536 + tok] = f1;
    ((unsigned char*)(ws + WS_RESB))[h * 65536 + tok] =
        (unsigned char)(fc | (nt ? 0x80 : 0));
  }
}

// ---------------- Kernel M: exact 4-way merge -> fidx/flags + loss partials ----
// flag <=> (within-winner-quarter gap < TAU) OR (cross-quarter winner gap < TAU)
// == (true global top-2 gap < TAU).
__global__ __launch_bounds__(256) void k_merge(const float* __restrict__ emb,
    float* __restrict__ dout, char* __restrict__ ws)
{
  __shared__ float ls[4];
  const int v = blockIdx.x * 256 + threadIdx.x;
  const unsigned* resw = (const unsigned*)(ws + WS_RESW);
  const unsigned char* resb = (const unsigned char*)(ws + WS_RESB);
  unsigned k1 = 0xffffffffu, k2 = 0xffffffffu, bw = 0; int bq = 0;
#pragma unroll
  for (int q = 0; q < 4; ++q) {
    const unsigned W = resw[q * 65536 + v];
    const unsigned key = W & ~63u;
    if (key < k1) { k2 = k1; k1 = key; bq = q; bw = W; }
    else          { k2 = key < k2 ? key : k2; }
  }
  const unsigned char b = resb[bq * 65536 + v];
  const int code = bq * 1024 + (int)(b & 15u) * 64 + (int)(bw & 63u);
  dout[OUT_ELEMS + 2 + v] = (float)code;
  const bool flag = (b & 0x80u) ||
                    (__uint_as_float(k2) - __uint_as_float(k1) < TAU);
  if (flag) {
    int p = atomicAdd((int*)(ws + WS_CNT), 1);
    if (p < FLAG_CAP) ((int*)(ws + WS_FLAG))[p] = v;
  }
  // loss: sum (t - q)^2 for this token
  const float* tcol = dout + v;                // t[c][v]
  const float* q = emb + (size_t)code * 64;
  float acc = 0.f;
#pragma unroll
  for (int cch = 0; cch < 64; ++cch) {
    const float d = tcol[(size_t)cch * NTOK] - q[cch];
    acc = fmaf(d, d, acc);
  }
#pragma unroll
  for (int m = 1; m < 64; m <<= 1) acc += __shfl_xor(acc, m);
  const int lane = threadIdx.x & 63, wv = threadIdx.x >> 6;
  if (lane == 0) ls[wv] = acc;
  __syncthreads();
  if (threadIdx.x == 0)
    ((float*)(ws + WS_PART))[blockIdx.x] = ls[0] + ls[1] + ls[2] + ls[3];
}

// ---------------- Kernel R: f64 re-scan of near-tie tokens --------------------
// Wave-per-token, 4/block, direct emb scan (L2-resident), no LDS tiles, no
// in-loop barriers. Lane owns code = it*64+lane; all 64 t-channels in regs
// (static-indexed -> no scratch). Few tokens flagged -> spread across CUs.
__global__ __launch_bounds__(256) void k_refine(const float* __restrict__ z,
    const float* __restrict__ emb, const float* __restrict__ pw, const float* __restrict__ pb,
    float* __restrict__ dout, char* __restrict__ ws)
{
  __shared__ double tdsh[4][64];
  int cv = *(const int*)(ws + WS_CNT);
  if (cv > FLAG_CAP) cv = FLAG_CAP;
  const int base = blockIdx.x * 4;
  if (base >= cv) return;
  const int tid = threadIdx.x;
  const int w = tid >> 6, lane = tid & 63;
  const int slot = base + w;
  const bool active = slot < cv;
  const int n = active ? ((const int*)(ws + WS_FLAG))[slot] : 0;

  if (active) {                                    // recompute token t in f64
    const int b = n >> 15, r = n & (DHW - 1);
    const float* zp = z + (size_t)b * 64 * DHW + r;
    const float* wr = pw + lane * 64;
    double a = (double)pb[lane];
    for (int c2 = 0; c2 < 64; ++c2)
      a = fma((double)wr[c2], (double)zp[(size_t)c2 * DHW], a);
    tdsh[w][lane] = a;
  }
  __syncthreads();
  if (!active) return;

  double td[64];                                   // all channels, static-indexed
#pragma unroll
  for (int j = 0; j < 64; ++j) td[j] = tdsh[w][j]; // broadcast reads

  double dmin = 1e300; int kmin = 0;
  for (int it = 0; it < 64; ++it) {
    const float4* e = (const float4*)(emb + (size_t)(it * 64 + lane) * 64);
    double d0 = 0.0, d1 = 0.0;
#pragma unroll
    for (int i = 0; i < 16; ++i) {
      const float4 ev = e[i];
      const double x0 = td[4 * i]     - (double)ev.x; d0 = fma(x0, x0, d0);
      const double x1 = td[4 * i + 1] - (double)ev.y; d1 = fma(x1, x1, d1);
      const double x2 = td[4 * i + 2] - (double)ev.z; d0 = fma(x2, x2, d0);
      const double x3 = td[4 * i + 3] - (double)ev.w; d1 = fma(x3, x3, d1);
    }
    const double d = d0 + d1;
    const int code = it * 64 + lane;
    if (d < dmin) { dmin = d; kmin = code; }       // ascending codes per lane
  }
#pragma unroll
  for (int m = 1; m < 64; m <<= 1) {               // argmin, lower-code tiebreak
    const double od = __shfl_xor(dmin, m);
    const int    ok = __shfl_xor(kmin, m);
    if (od < dmin || (od == dmin && ok < kmin)) { dmin = od; kmin = ok; }
  }
  if (lane == 0) dout[OUT_ELEMS + 2 + n] = (float)kmin;
}

// ---------------- Kernel D: post-conv (out = post_w@q + post_b) + loss final ---
// code read back from fidx (float-encoded, exact for < 2^24).
__global__ __launch_bounds__(256) void k_post(const float* __restrict__ emb,
    const float* __restrict__ ow, const float* __restrict__ ob,
    float* __restrict__ dout, const char* __restrict__ ws)
{
  __shared__ float ps[256];
  const int v = blockIdx.x * 256 + threadIdx.x;
  const int b = v >> 15, r = v & (DHW - 1);
  const int code = (int)dout[OUT_ELEMS + 2 + v];
  const float* q = emb + (size_t)code * 64;
  float qr[64];
#pragma unroll
  for (int i = 0; i < 64; ++i) qr[i] = q[i];
  float* op = dout + (size_t)b * 64 * DHW + r;
  for (int o = 0; o < 64; ++o) {              // o uniform -> post_w row via s_load
    float a = ob[o];
    const float* wr = ow + o * 64;
#pragma unroll
    for (int cch = 0; cch < 64; ++cch) a = fmaf(wr[cch], qr[cch], a);
    op[(size_t)o * DHW] = a;                  // coalesced
  }
  if (blockIdx.x == 0) {
    ps[threadIdx.x] = ((const float*)(ws + WS_PART))[threadIdx.x];
    __syncthreads();
    if (threadIdx.x == 0) {
      float s = 0.f;
      for (int i = 0; i < 256; ++i) s += ps[i];   // fixed order: deterministic
      const float mean = s / 4194304.0f;
      dout[OUT_ELEMS]     = mean;   // codebook_loss
      dout[OUT_ELEMS + 1] = mean;   // commitment_loss
    }
  }
}

extern "C" void kernel_launch(void* const* d_in, const int* in_sizes, int n_in,
                              void* d_out, int out_size, void* d_ws, size_t ws_size,
                              hipStream_t stream) {
  (void)in_sizes; (void)n_in; (void)out_size; (void)ws_size;
  const float* z   = (const float*)d_in[0];
  const float* emb = (const float*)d_in[1];
  const float* pw  = (const float*)d_in[2];
  const float* pb  = (const float*)d_in[3];
  const float* ow  = (const float*)d_in[4];
  const float* ob  = (const float*)d_in[5];
  float* out = (float*)d_out;
  char*  ws  = (char*)d_ws;

  hipLaunchKernelGGL(k_pre,    dim3(320),  dim3(256), 0, stream, z, emb, pw, pb, out, ws);
  hipLaunchKernelGGL(k_dist,   dim3(1024), dim3(512), 0, stream, out, ws);
  hipLaunchKernelGGL(k_merge,  dim3(256),  dim3(256), 0, stream, emb, out, ws);
  hipLaunchKernelGGL(k_refine, dim3(FLAG_CAP / 4), dim3(256), 0, stream, z, emb, pw, pb, out, ws);
  hipLaunchKernelGGL(k_post,   dim3(256),  dim3(256), 0, stream, emb, ow, ob, out, ws);
}

// Round 7
// 240.763 us; speedup vs baseline: 1.4494x; 1.3587x over previous
//
#include <hip/hip_runtime.h>
#include <cstdint>
#include <cstddef>

typedef float  f32x4  __attribute__((ext_vector_type(4)));
typedef float  f32x16 __attribute__((ext_vector_type(16)));
typedef short  s16x8  __attribute__((ext_vector_type(8)));

#define DEV __device__ __forceinline__

static constexpr int    DHW       = 32768;       // 8*64*64
static constexpr int    NTOK      = 65536;       // B*D*H*W
static constexpr int    CHUNK_B   = 18432;       // 16384 gh/gl + 1KB e2 + zero slot + pad
static constexpr size_t OUT_ELEMS = 4194304;     // 2*64*32768
static constexpr float  BIGC      = 512.0f;      // positivity bias for uint-compare
static constexpr float  TAU       = 0.015f;      // near-tie refinement threshold
static constexpr int    FLAG_CAP  = 8192;

// workspace layout (end = 2,524,416 B)
static constexpr size_t WS_PREP = 0;             // 64*18432 = 1,179,648
static constexpr size_t WS_RESW = 1179648;       // 4*65536*4 (per-quarter winner word)
static constexpr size_t WS_RESB = 2228224;       // 4*65536*1 (chunk | tie-bit)
static constexpr size_t WS_PART = 2490368;       // 256*4
static constexpr size_t WS_CNT  = 2491392;       // int
static constexpr size_t WS_FLAG = 2491648;       // FLAG_CAP*4 -> end 2,524,416

DEV unsigned f2bf(float f) {            // RNE float -> bf16 bits
  unsigned u = __float_as_uint(f);
  return (u + 0x7FFFu + ((u >> 16) & 1u)) >> 16;
}
DEV float bf2f(unsigned h) { return __uint_as_float(h << 16); }
DEV unsigned med3u(unsigned a, unsigned b, unsigned c) {
  unsigned r;
  asm("v_med3_u32 %0, %1, %2, %3" : "=v"(r) : "v"(a), "v"(b), "v"(c));
  return r;
}
DEV void gl_lds16(const void* g, void* l) {   // 64 lanes x 16B, dest = base + lane*16
  __builtin_amdgcn_global_load_lds(
      (const __attribute__((address_space(1))) unsigned int*)g,
      (__attribute__((address_space(3))) unsigned int*)l, 16, 0, 0);
}

// ---------------- Kernel A: pre-conv (t = pre_w@z + pre_b) + embedding prep ----
// t stored [C=64][NTOK] inside d_out (overwritten later by k_post).
__global__ __launch_bounds__(256) void k_pre(const float* __restrict__ z,
    const float* __restrict__ emb, const float* __restrict__ pw, const float* __restrict__ pb,
    float* __restrict__ dout, char* __restrict__ ws)
{
  const int blk = blockIdx.x, tid = threadIdx.x;
  if (blk == 0 && tid == 0) *(int*)(ws + WS_CNT) = 0;
  if (blk < 256) {
    float* t = dout;
    const int v = blk * 256 + tid;
    const int b = v >> 15, r = v & (DHW - 1);
    const float* zp = z + (size_t)b * 64 * DHW + r;
    float zr[64];
#pragma unroll
    for (int c2 = 0; c2 < 64; ++c2) zr[c2] = zp[(size_t)c2 * DHW];
    for (int c = 0; c < 64; ++c) {          // c uniform -> pre_w row via s_load
      float a = pb[c];
      const float* wr = pw + c * 64;
#pragma unroll
      for (int c2 = 0; c2 < 64; ++c2) a = fmaf(wr[c2], zr[c2], a);
      t[(size_t)c * NTOK + v] = a;          // coalesced across lanes
    }
  } else {
    const int tt = (blk - 256) * 256 + tid;  // 0..16383, 2 units each
#pragma unroll
    for (int uu = 0; uu < 2; ++uu) {
      const int u = tt * 2 + uu;
      const int k = u >> 3, j = u & 7;       // code k, 8-channel group j
      const float* ep = emb + (size_t)k * 64 + j * 8;
      unsigned hw[4], lw[4];
#pragma unroll
      for (int i = 0; i < 4; ++i) {
        float g0 = -2.0f * ep[2 * i], g1 = -2.0f * ep[2 * i + 1];
        unsigned h0 = f2bf(g0); unsigned l0 = f2bf(g0 - bf2f(h0));
        unsigned h1 = f2bf(g1); unsigned l1 = f2bf(g1 - bf2f(h1));
        hw[i] = h0 | (h1 << 16); lw[i] = l0 | (l1 << 16);
      }
      char* base = ws + WS_PREP + (size_t)(k >> 6) * CHUNK_B;
      const int r = k & 63;
      const int swz = (r & 15) << 4;
      char* rowp = base + r * 256;
      *(uint4*)(rowp + ((j * 16) ^ swz))        = make_uint4(hw[0], hw[1], hw[2], hw[3]);
      *(uint4*)(rowp + ((128 + j * 16) ^ swz))  = make_uint4(lw[0], lw[1], lw[2], lw[3]);
      if (j == 0) {
        const float* er = emb + (size_t)k * 64;
        float s = 0.f;
#pragma unroll
        for (int c = 0; c < 64; ++c) s = fmaf(er[c], er[c], s);
        s += BIGC;
        unsigned eh  = f2bf(s);
        float    rs  = s - bf2f(eh);
        unsigned el  = f2bf(rs);
        unsigned el2 = f2bf(rs - bf2f(el));
        *(uint4*)(base + 16384 + r * 16) = make_uint4(eh | (el << 16), el2, 0u, 0u);
        if (r == 0) *(uint4*)(base + 16384 + 1024) = make_uint4(0u, 0u, 0u, 0u);
      }
    }
  }
}

// ---------------- Kernel B: bf16x3 MFMA distance (32x32x16), 4-way chunk split -
// grid = 1024 blocks x 512 thr. Block: tokens (bid>>2)*256..+256,
// chunks (bid&3)*16..+16. e2 folded via one extra MFMA per rowtile.
__global__ __launch_bounds__(512, 4) void k_dist(float* __restrict__ dout,
                                                 char* __restrict__ ws)
{
  constexpr int NCH = 16;
  __shared__ __align__(16) char smem[2 * CHUNK_B];
  const float* t = dout;                       // [64][NTOK]
  const int tid = threadIdx.x;
  const int w = tid >> 6, lane = tid & 63;
  const int l31 = lane & 31, khalf = lane >> 5;
  const int gidx = blockIdx.x >> 2, h = blockIdx.x & 3;
  const int tb = gidx * 256 + w * 32;
  const int tok = tb + l31;

  // ---- B-fragments: t[k][tok], k = kt*16 + khalf*8 + i ----
  s16x8 tav[4], tlv[4];
#pragma unroll
  for (int kt = 0; kt < 4; ++kt) {
    const float* tc = t + (size_t)(kt * 16 + khalf * 8) * NTOK + tok;
    float f[8];
#pragma unroll
    for (int i = 0; i < 8; ++i) f[i] = tc[(size_t)i * NTOK];
    union { unsigned u[4]; s16x8 v; } xh, xl;
#pragma unroll
    for (int i = 0; i < 4; ++i) {
      unsigned h0 = f2bf(f[2 * i]),     l0 = f2bf(f[2 * i]     - bf2f(h0));
      unsigned h1 = f2bf(f[2 * i + 1]), l1 = f2bf(f[2 * i + 1] - bf2f(h1));
      xh.u[i] = h0 | (h1 << 16); xl.u[i] = l0 | (l1 << 16);
    }
    tav[kt] = xh.v; tlv[kt] = xl.v;
  }
  s16x8 ones;                                  // B for e2-MFMA: k'=0,1,2 -> 1.0 (khalf 0)
  { union { unsigned u[4]; s16x8 v; } o;
    o.u[0] = khalf ? 0u : 0x3F803F80u;
    o.u[1] = khalf ? 0u : 0x00003F80u;
    o.u[2] = 0u; o.u[3] = 0u; ones = o.v; }

  const char* prep = ws + WS_PREP + (size_t)h * NCH * CHUNK_B;
  const int swz = (l31 & 15) << 4;

  // prologue: stage chunk 0 (linear copy: prep is pre-swizzled)
  {
    const char* src = prep;
    gl_lds16(src + w * 1024 + lane * 16, smem + w * 1024);
    gl_lds16(src + 8192 + w * 1024 + lane * 16, smem + 8192 + w * 1024);
    if (w < 2) gl_lds16(src + 16384 + w * 1024 + lane * 16, smem + 16384 + w * 1024);
  }
  __syncthreads();

  unsigned u1 = 0x7f800000u, u2 = 0x7f800000u;
  int c1 = 0;

  for (int c = 0; c < NCH; ++c) {
    const char* L = smem + (c & 1) * CHUNK_B;
    if (c + 1 < NCH) {                         // issue next-chunk stage early
      const char* src = prep + (size_t)(c + 1) * CHUNK_B;
      char* dst = smem + ((c + 1) & 1) * CHUNK_B;
      gl_lds16(src + w * 1024 + lane * 16, dst + w * 1024);
      gl_lds16(src + 8192 + w * 1024 + lane * 16, dst + 8192 + w * 1024);
      if (w < 2) gl_lds16(src + 16384 + w * 1024 + lane * 16, dst + 16384 + w * 1024);
    }
    f32x16 acc0 = {}, acc1 = {};
    {                                          // e2 seed via MFMA (adds 512+||e||^2)
      const s16x8 e0 = *(const s16x8*)(L + (khalf ? (16384 + 1024) : (16384 + l31 * 16)));
      const s16x8 e1 = *(const s16x8*)(L + (khalf ? (16384 + 1024) : (16384 + (32 + l31) * 16)));
      acc0 = __builtin_amdgcn_mfma_f32_32x32x16_bf16(e0, ones, acc0, 0, 0, 0);
      acc1 = __builtin_amdgcn_mfma_f32_32x32x16_bf16(e1, ones, acc1, 0, 0, 0);
    }
#pragma unroll
    for (int kt = 0; kt < 4; ++kt) {
      const int i0 = (kt * 32 + khalf * 16) ^ swz;
      const s16x8 gh0 = *(const s16x8*)(L + l31 * 256 + i0);
      const s16x8 gl0 = *(const s16x8*)(L + l31 * 256 + (i0 ^ 128));
      const s16x8 gh1 = *(const s16x8*)(L + (32 + l31) * 256 + i0);
      const s16x8 gl1 = *(const s16x8*)(L + (32 + l31) * 256 + (i0 ^ 128));
      acc0 = __builtin_amdgcn_mfma_f32_32x32x16_bf16(gh0, tav[kt], acc0, 0, 0, 0);
      acc0 = __builtin_amdgcn_mfma_f32_32x32x16_bf16(gh0, tlv[kt], acc0, 0, 0, 0);
      acc0 = __builtin_amdgcn_mfma_f32_32x32x16_bf16(gl0, tav[kt], acc0, 0, 0, 0);
      acc1 = __builtin_amdgcn_mfma_f32_32x32x16_bf16(gh1, tav[kt], acc1, 0, 0, 0);
      acc1 = __builtin_amdgcn_mfma_f32_32x32x16_bf16(gh1, tlv[kt], acc1, 0, 0, 0);
      acc1 = __builtin_amdgcn_mfma_f32_32x32x16_bf16(gl1, tav[kt], acc1, 0, 0, 0);
    }
    // argmin: C row = rt*32 + (q&3) + 8*(q>>2) + 4*khalf; khalf bit |'d at end
    const unsigned p1 = u1;
#pragma unroll
    for (int q = 0; q < 16; ++q) {
      const unsigned w0 = (unsigned)((q & 3) + 8 * (q >> 2));
      unsigned v0 = (__float_as_uint(acc0[q]) & ~63u) | w0;
      u2 = med3u(u1, v0, u2); u1 = u1 < v0 ? u1 : v0;
      unsigned v1 = (__float_as_uint(acc1[q]) & ~63u) | (w0 + 32u);
      u2 = med3u(u1, v1, u2); u1 = u1 < v1 ? u1 : v1;
    }
    if (u1 != p1) c1 = c;
    __syncthreads();                           // drains vmcnt -> next chunk staged
  }

  u1 |= (unsigned)(khalf * 4);                 // complete wid (bit 2)
  // merge lane <-> lane+32 (same token, different code rows)
  const unsigned o1 = __shfl_xor(u1, 32);
  const unsigned o2 = __shfl_xor(u2, 32);
  const int      oc = __shfl_xor(c1, 32);
  const unsigned am = u1 & ~63u, om = o1 & ~63u;
  const int mycode = c1 * 64 + (int)(u1 & 63u);
  const int ocode  = oc * 64 + (int)(o1 & 63u);
  const bool owins = (om < am) || (om == am && ocode < mycode);
  const unsigned f1 = owins ? o1 : u1;
  const int      fc = owins ? oc : c1;
  const unsigned mx = owins ? am : om;
  unsigned s2 = (u2 & ~63u) < (o2 & ~63u) ? (u2 & ~63u) : (o2 & ~63u);
  s2 = s2 < mx ? s2 : mx;
  if (khalf == 0) {
    const bool nt = (__uint_as_float(s2) - __uint_as_float(f1 & ~63u)) < TAU;
    ((unsigned*)(ws + WS_RESW))[h * 65536 + tok] = f1;
    ((unsigned char*)(ws + WS_RESB))[h * 65536 + tok] =
        (unsigned char)(fc | (nt ? 0x80 : 0));
  }
}

// ---------------- Kernel M: exact 4-way merge -> fidx/flags + loss partials ----
__global__ __launch_bounds__(256) void k_merge(const float* __restrict__ emb,
    float* __restrict__ dout, char* __restrict__ ws)
{
  __shared__ float ls[4];
  const int v = blockIdx.x * 256 + threadIdx.x;
  const unsigned* resw = (const unsigned*)(ws + WS_RESW);
  const unsigned char* resb = (const unsigned char*)(ws + WS_RESB);
  unsigned k1 = 0xffffffffu, k2 = 0xffffffffu, bw = 0; int bq = 0;
#pragma unroll
  for (int q = 0; q < 4; ++q) {
    const unsigned W = resw[q * 65536 + v];
    const unsigned key = W & ~63u;
    if (key < k1) { k2 = k1; k1 = key; bq = q; bw = W; }
    else          { k2 = key < k2 ? key : k2; }
  }
  const unsigned char b = resb[bq * 65536 + v];
  const int code = bq * 1024 + (int)(b & 15u) * 64 + (int)(bw & 63u);
  dout[OUT_ELEMS + 2 + v] = (float)code;
  const bool flag = (b & 0x80u) ||
                    (__uint_as_float(k2) - __uint_as_float(k1) < TAU);
  if (flag) {
    int p = atomicAdd((int*)(ws + WS_CNT), 1);
    if (p < FLAG_CAP) ((int*)(ws + WS_FLAG))[p] = v;
  }
  // loss: sum (t - q)^2 for this token
  const float* tcol = dout + v;                // t[c][v]
  const float* q = emb + (size_t)code * 64;
  float acc = 0.f;
#pragma unroll
  for (int cch = 0; cch < 64; ++cch) {
    const float d = tcol[(size_t)cch * NTOK] - q[cch];
    acc = fmaf(d, d, acc);
  }
#pragma unroll
  for (int m = 1; m < 64; m <<= 1) acc += __shfl_xor(acc, m);
  const int lane = threadIdx.x & 63, wv = threadIdx.x >> 6;
  if (lane == 0) ls[wv] = acc;
  __syncthreads();
  if (threadIdx.x == 0)
    ((float*)(ws + WS_PART))[blockIdx.x] = ls[0] + ls[1] + ls[2] + ls[3];
}

// ---------------- Kernel R: f64 re-scan of near-tie tokens --------------------
// BLOCK-per-token (256 thr): thread scans 16 codes {tid, 256+tid, ...} with the
// PROVEN per-code ACC4 f64 order (only code->thread mapping changed vs r6).
// 4x parallelism per token + 4 waves of TLP; no in-loop barriers, no LDS tiles.
__global__ __launch_bounds__(256) void k_refine(const float* __restrict__ z,
    const float* __restrict__ emb, const float* __restrict__ pw, const float* __restrict__ pb,
    float* __restrict__ dout, char* __restrict__ ws)
{
  __shared__ double tdsh[64];
  __shared__ double dred[4]; __shared__ int kred[4];
  int cv = *(const int*)(ws + WS_CNT);
  if (cv > FLAG_CAP) cv = FLAG_CAP;
  const int slot = blockIdx.x;
  if (slot >= cv) return;
  const int tid = threadIdx.x;
  const int lane = tid & 63, wv = tid >> 6;
  const int n = ((const int*)(ws + WS_FLAG))[slot];

  if (tid < 64) {                                  // recompute token t in f64 (proven chain)
    const int b = n >> 15, r = n & (DHW - 1);
    const float* zp = z + (size_t)b * 64 * DHW + r;
    const float* wr = pw + tid * 64;
    double a = (double)pb[tid];
    for (int c2 = 0; c2 < 64; ++c2)
      a = fma((double)wr[c2], (double)zp[(size_t)c2 * DHW], a);
    tdsh[tid] = a;
  }
  __syncthreads();

  double td[64];                                   // all channels, static-indexed
#pragma unroll
  for (int j = 0; j < 64; ++j) td[j] = tdsh[j];    // broadcast reads

  double dmin = 1e300; int kmin = 0;
  for (int it = 0; it < 16; ++it) {
    const int code = it * 256 + tid;               // ascending per thread
    const float4* e = (const float4*)(emb + (size_t)code * 64);
    double d0 = 0.0, d1 = 0.0;
#pragma unroll
    for (int i = 0; i < 16; ++i) {
      const float4 ev = e[i];
      const double x0 = td[4 * i]     - (double)ev.x; d0 = fma(x0, x0, d0);
      const double x1 = td[4 * i + 1] - (double)ev.y; d1 = fma(x1, x1, d1);
      const double x2 = td[4 * i + 2] - (double)ev.z; d0 = fma(x2, x2, d0);
      const double x3 = td[4 * i + 3] - (double)ev.w; d1 = fma(x3, x3, d1);
    }
    const double d = d0 + d1;
    if (d < dmin) { dmin = d; kmin = code; }       // strict < -> lowest code kept
  }
#pragma unroll
  for (int m = 1; m < 64; m <<= 1) {               // wave argmin, lower-code tiebreak
    const double od = __shfl_xor(dmin, m);
    const int    ok = __shfl_xor(kmin, m);
    if (od < dmin || (od == dmin && ok < kmin)) { dmin = od; kmin = ok; }
  }
  if (lane == 0) { dred[wv] = dmin; kred[wv] = kmin; }
  __syncthreads();
  if (tid == 0) {
#pragma unroll
    for (int i = 1; i < 4; ++i)
      if (dred[i] < dmin || (dred[i] == dmin && kred[i] < kmin)) { dmin = dred[i]; kmin = kred[i]; }
    dout[OUT_ELEMS + 2 + n] = (float)kmin;
  }
}

// ---------------- Kernel D: post-conv (out = post_w@q + post_b) + loss final ---
// code read back from fidx (float-encoded, exact for < 2^24).
__global__ __launch_bounds__(256) void k_post(const float* __restrict__ emb,
    const float* __restrict__ ow, const float* __restrict__ ob,
    float* __restrict__ dout, const char* __restrict__ ws)
{
  __shared__ float ps[256];
  const int v = blockIdx.x * 256 + threadIdx.x;
  const int b = v >> 15, r = v & (DHW - 1);
  const int code = (int)dout[OUT_ELEMS + 2 + v];
  const float* q = emb + (size_t)code * 64;
  float qr[64];
#pragma unroll
  for (int i = 0; i < 64; ++i) qr[i] = q[i];
  float* op = dout + (size_t)b * 64 * DHW + r;
  for (int o = 0; o < 64; ++o) {              // o uniform -> post_w row via s_load
    float a = ob[o];
    const float* wr = ow + o * 64;
#pragma unroll
    for (int cch = 0; cch < 64; ++cch) a = fmaf(wr[cch], qr[cch], a);
    op[(size_t)o * DHW] = a;                  // coalesced
  }
  if (blockIdx.x == 0) {
    ps[threadIdx.x] = ((const float*)(ws + WS_PART))[threadIdx.x];
    __syncthreads();
    if (threadIdx.x == 0) {
      float s = 0.f;
      for (int i = 0; i < 256; ++i) s += ps[i];   // fixed order: deterministic
      const float mean = s / 4194304.0f;
      dout[OUT_ELEMS]     = mean;   // codebook_loss
      dout[OUT_ELEMS + 1] = mean;   // commitment_loss
    }
  }
}

extern "C" void kernel_launch(void* const* d_in, const int* in_sizes, int n_in,
                              void* d_out, int out_size, void* d_ws, size_t ws_size,
                              hipStream_t stream) {
  (void)in_sizes; (void)n_in; (void)out_size; (void)ws_size;
  const float* z   = (const float*)d_in[0];
  const float* emb = (const float*)d_in[1];
  const float* pw  = (const float*)d_in[2];
  const float* pb  = (const float*)d_in[3];
  const float* ow  = (const float*)d_in[4];
  const float* ob  = (const float*)d_in[5];
  float* out = (float*)d_out;
  char*  ws  = (char*)d_ws;

  hipLaunchKernelGGL(k_pre,    dim3(320),  dim3(256), 0, stream, z, emb, pw, pb, out, ws);
  hipLaunchKernelGGL(k_dist,   dim3(1024), dim3(512), 0, stream, out, ws);
  hipLaunchKernelGGL(k_merge,  dim3(256),  dim3(256), 0, stream, emb, out, ws);
  hipLaunchKernelGGL(k_refine, dim3(FLAG_CAP), dim3(256), 0, stream, z, emb, pw, pb, out, ws);
  hipLaunchKernelGGL(k_post,   dim3(256),  dim3(256), 0, stream, emb, ow, ob, out, ws);
}

// Round 8
// 196.619 us; speedup vs baseline: 1.7748x; 1.2245x over previous
//
#include <hip/hip_runtime.h>
#include <cstdint>
#include <cstddef>

typedef float  f32x4  __attribute__((ext_vector_type(4)));
typedef float  f32x16 __attribute__((ext_vector_type(16)));
typedef short  s16x8  __attribute__((ext_vector_type(8)));

#define DEV __device__ __forceinline__

static constexpr int    DHW       = 32768;       // 8*64*64
static constexpr int    NTOK      = 65536;       // B*D*H*W
static constexpr int    CHUNK_B   = 18432;       // 16384 gh/gl + 1KB e2 + zero slot + pad
static constexpr size_t OUT_ELEMS = 4194304;     // 2*64*32768
static constexpr float  BIGC      = 512.0f;      // positivity bias for uint-compare
static constexpr float  TAU       = 0.015f;      // near-tie refinement threshold
static constexpr int    FLAG_CAP  = 7424;        // sized so ws end == 2,524,416 (proven)

// workspace layout (end = 2,524,416 B)
static constexpr size_t WS_PREP = 0;             // 64*18432 = 1,179,648
static constexpr size_t WS_RESW = 1179648;       // 2*65536*4 (per-half winner word; 4-slot area kept)
static constexpr size_t WS_RESB = 2228224;       // 2*65536*1 (chunk | tie-bit)
static constexpr size_t WS_PART = 2490368;       // 1024*4
static constexpr size_t WS_CNT  = 2494464;       // int
static constexpr size_t WS_FLAG = 2494720;       // FLAG_CAP*4 -> end 2,524,416

DEV unsigned f2bf(float f) {            // RNE float -> bf16 bits
  unsigned u = __float_as_uint(f);
  return (u + 0x7FFFu + ((u >> 16) & 1u)) >> 16;
}
DEV float bf2f(unsigned h) { return __uint_as_float(h << 16); }
DEV unsigned med3u(unsigned a, unsigned b, unsigned c) {
  unsigned r;
  asm("v_med3_u32 %0, %1, %2, %3" : "=v"(r) : "v"(a), "v"(b), "v"(c));
  return r;
}
DEV void gl_lds16(const void* g, void* l) {   // 64 lanes x 16B, dest = base + lane*16
  __builtin_amdgcn_global_load_lds(
      (const __attribute__((address_space(1))) unsigned int*)g,
      (__attribute__((address_space(3))) unsigned int*)l, 16, 0, 0);
}

// ---------------- Kernel A: pre-conv (t = pre_w@z + pre_b) + embedding prep ----
// t stored [C=64][NTOK] inside d_out (overwritten later by k_post).
__global__ __launch_bounds__(256) void k_pre(const float* __restrict__ z,
    const float* __restrict__ emb, const float* __restrict__ pw, const float* __restrict__ pb,
    float* __restrict__ dout, char* __restrict__ ws)
{
  const int blk = blockIdx.x, tid = threadIdx.x;
  if (blk == 0 && tid == 0) *(int*)(ws + WS_CNT) = 0;
  if (blk < 256) {
    float* t = dout;
    const int v = blk * 256 + tid;
    const int b = v >> 15, r = v & (DHW - 1);
    const float* zp = z + (size_t)b * 64 * DHW + r;
    float zr[64];
#pragma unroll
    for (int c2 = 0; c2 < 64; ++c2) zr[c2] = zp[(size_t)c2 * DHW];
    for (int c = 0; c < 64; c += 4) {        // 4 independent chains (ILP)
      const float* w0 = pw + c * 64;
      const float* w1 = pw + (c + 1) * 64;
      const float* w2 = pw + (c + 2) * 64;
      const float* w3 = pw + (c + 3) * 64;
      float a0 = pb[c], a1 = pb[c + 1], a2 = pb[c + 2], a3 = pb[c + 3];
#pragma unroll
      for (int c2 = 0; c2 < 64; ++c2) {      // per-channel order unchanged
        const float zv = zr[c2];
        a0 = fmaf(w0[c2], zv, a0); a1 = fmaf(w1[c2], zv, a1);
        a2 = fmaf(w2[c2], zv, a2); a3 = fmaf(w3[c2], zv, a3);
      }
      t[(size_t)c * NTOK + v]       = a0;
      t[(size_t)(c + 1) * NTOK + v] = a1;
      t[(size_t)(c + 2) * NTOK + v] = a2;
      t[(size_t)(c + 3) * NTOK + v] = a3;
    }
  } else {
    const int tt = (blk - 256) * 256 + tid;  // 0..16383, 2 units each
#pragma unroll
    for (int uu = 0; uu < 2; ++uu) {
      const int u = tt * 2 + uu;
      const int k = u >> 3, j = u & 7;       // code k, 8-channel group j
      const float* ep = emb + (size_t)k * 64 + j * 8;
      unsigned hw[4], lw[4];
#pragma unroll
      for (int i = 0; i < 4; ++i) {
        float g0 = -2.0f * ep[2 * i], g1 = -2.0f * ep[2 * i + 1];
        unsigned h0 = f2bf(g0); unsigned l0 = f2bf(g0 - bf2f(h0));
        unsigned h1 = f2bf(g1); unsigned l1 = f2bf(g1 - bf2f(h1));
        hw[i] = h0 | (h1 << 16); lw[i] = l0 | (l1 << 16);
      }
      char* base = ws + WS_PREP + (size_t)(k >> 6) * CHUNK_B;
      const int r = k & 63;
      const int swz = (r & 15) << 4;
      char* rowp = base + r * 256;
      *(uint4*)(rowp + ((j * 16) ^ swz))        = make_uint4(hw[0], hw[1], hw[2], hw[3]);
      *(uint4*)(rowp + ((128 + j * 16) ^ swz))  = make_uint4(lw[0], lw[1], lw[2], lw[3]);
      if (j == 0) {
        const float* er = emb + (size_t)k * 64;
        float s = 0.f;
#pragma unroll
        for (int c = 0; c < 64; ++c) s = fmaf(er[c], er[c], s);
        s += BIGC;
        unsigned eh  = f2bf(s);
        float    rs  = s - bf2f(eh);
        unsigned el  = f2bf(rs);
        unsigned el2 = f2bf(rs - bf2f(el));
        *(uint4*)(base + 16384 + r * 16) = make_uint4(eh | (el << 16), el2, 0u, 0u);
        if (r == 0) *(uint4*)(base + 16384 + 1024) = make_uint4(0u, 0u, 0u, 0u);
      }
    }
  }
}

// ---------------- Kernel B: bf16x3 MFMA distance (32x32x16), 2-way chunk split -
// grid = 512 blocks x 512 thr. Block: tokens (bid>>1)*256..+256, chunks (bid&1)*32..+32.
__global__ __launch_bounds__(512, 4) void k_dist(float* __restrict__ dout,
                                                 char* __restrict__ ws)
{
  constexpr int NCH = 32;
  __shared__ __align__(16) char smem[2 * CHUNK_B];
  const float* t = dout;                       // [64][NTOK]
  const int tid = threadIdx.x;
  const int w = tid >> 6, lane = tid & 63;
  const int l31 = lane & 31, khalf = lane >> 5;
  const int gidx = blockIdx.x >> 1, h = blockIdx.x & 1;
  const int tb = gidx * 256 + w * 32;
  const int tok = tb + l31;

  // ---- B-fragments: t[k][tok], k = kt*16 + khalf*8 + i ----
  s16x8 tav[4], tlv[4];
#pragma unroll
  for (int kt = 0; kt < 4; ++kt) {
    const float* tc = t + (size_t)(kt * 16 + khalf * 8) * NTOK + tok;
    float f[8];
#pragma unroll
    for (int i = 0; i < 8; ++i) f[i] = tc[(size_t)i * NTOK];
    union { unsigned u[4]; s16x8 v; } xh, xl;
#pragma unroll
    for (int i = 0; i < 4; ++i) {
      unsigned h0 = f2bf(f[2 * i]),     l0 = f2bf(f[2 * i]     - bf2f(h0));
      unsigned h1 = f2bf(f[2 * i + 1]), l1 = f2bf(f[2 * i + 1] - bf2f(h1));
      xh.u[i] = h0 | (h1 << 16); xl.u[i] = l0 | (l1 << 16);
    }
    tav[kt] = xh.v; tlv[kt] = xl.v;
  }
  s16x8 ones;                                  // B for e2-MFMA: k'=0,1,2 -> 1.0 (khalf 0)
  { union { unsigned u[4]; s16x8 v; } o;
    o.u[0] = khalf ? 0u : 0x3F803F80u;
    o.u[1] = khalf ? 0u : 0x00003F80u;
    o.u[2] = 0u; o.u[3] = 0u; ones = o.v; }

  const char* prep = ws + WS_PREP + (size_t)h * NCH * CHUNK_B;
  const int swz = (l31 & 15) << 4;

  // prologue: stage chunk 0 (linear copy: prep is pre-swizzled)
  {
    const char* src = prep;
    gl_lds16(src + w * 1024 + lane * 16, smem + w * 1024);
    gl_lds16(src + 8192 + w * 1024 + lane * 16, smem + 8192 + w * 1024);
    if (w < 2) gl_lds16(src + 16384 + w * 1024 + lane * 16, smem + 16384 + w * 1024);
  }
  __syncthreads();

  unsigned u1 = 0x7f800000u, u2 = 0x7f800000u;
  int c1 = 0;

  for (int c = 0; c < NCH; ++c) {
    const char* L = smem + (c & 1) * CHUNK_B;
    if (c + 1 < NCH) {                         // issue next-chunk stage early
      const char* src = prep + (size_t)(c + 1) * CHUNK_B;
      char* dst = smem + ((c + 1) & 1) * CHUNK_B;
      gl_lds16(src + w * 1024 + lane * 16, dst + w * 1024);
      gl_lds16(src + 8192 + w * 1024 + lane * 16, dst + 8192 + w * 1024);
      if (w < 2) gl_lds16(src + 16384 + w * 1024 + lane * 16, dst + 16384 + w * 1024);
    }
    f32x16 acc0 = {}, acc1 = {};
    {                                          // e2 seed via MFMA (adds 512+||e||^2)
      const s16x8 e0 = *(const s16x8*)(L + (khalf ? (16384 + 1024) : (16384 + l31 * 16)));
      const s16x8 e1 = *(const s16x8*)(L + (khalf ? (16384 + 1024) : (16384 + (32 + l31) * 16)));
      acc0 = __builtin_amdgcn_mfma_f32_32x32x16_bf16(e0, ones, acc0, 0, 0, 0);
      acc1 = __builtin_amdgcn_mfma_f32_32x32x16_bf16(e1, ones, acc1, 0, 0, 0);
    }
#pragma unroll
    for (int kt = 0; kt < 4; ++kt) {
      const int i0 = (kt * 32 + khalf * 16) ^ swz;
      const s16x8 gh0 = *(const s16x8*)(L + l31 * 256 + i0);
      const s16x8 gl0 = *(const s16x8*)(L + l31 * 256 + (i0 ^ 128));
      const s16x8 gh1 = *(const s16x8*)(L + (32 + l31) * 256 + i0);
      const s16x8 gl1 = *(const s16x8*)(L + (32 + l31) * 256 + (i0 ^ 128));
      acc0 = __builtin_amdgcn_mfma_f32_32x32x16_bf16(gh0, tav[kt], acc0, 0, 0, 0);
      acc0 = __builtin_amdgcn_mfma_f32_32x32x16_bf16(gh0, tlv[kt], acc0, 0, 0, 0);
      acc0 = __builtin_amdgcn_mfma_f32_32x32x16_bf16(gl0, tav[kt], acc0, 0, 0, 0);
      acc1 = __builtin_amdgcn_mfma_f32_32x32x16_bf16(gh1, tav[kt], acc1, 0, 0, 0);
      acc1 = __builtin_amdgcn_mfma_f32_32x32x16_bf16(gh1, tlv[kt], acc1, 0, 0, 0);
      acc1 = __builtin_amdgcn_mfma_f32_32x32x16_bf16(gl1, tav[kt], acc1, 0, 0, 0);
    }
    // argmin: C row = rt*32 + (q&3) + 8*(q>>2) + 4*khalf; khalf bit |'d at end
    const unsigned p1 = u1;
#pragma unroll
    for (int q = 0; q < 16; ++q) {
      const unsigned w0 = (unsigned)((q & 3) + 8 * (q >> 2));
      unsigned v0 = (__float_as_uint(acc0[q]) & ~63u) | w0;
      u2 = med3u(u1, v0, u2); u1 = u1 < v0 ? u1 : v0;
      unsigned v1 = (__float_as_uint(acc1[q]) & ~63u) | (w0 + 32u);
      u2 = med3u(u1, v1, u2); u1 = u1 < v1 ? u1 : v1;
    }
    if (u1 != p1) c1 = c;
    __syncthreads();                           // drains vmcnt -> next chunk staged
  }

  u1 |= (unsigned)(khalf * 4);                 // complete wid (bit 2)
  // merge lane <-> lane+32 (same token, different code rows)
  const unsigned o1 = __shfl_xor(u1, 32);
  const unsigned o2 = __shfl_xor(u2, 32);
  const int      oc = __shfl_xor(c1, 32);
  const unsigned am = u1 & ~63u, om = o1 & ~63u;
  const int mycode = c1 * 64 + (int)(u1 & 63u);
  const int ocode  = oc * 64 + (int)(o1 & 63u);
  const bool owins = (om < am) || (om == am && ocode < mycode);
  const unsigned f1 = owins ? o1 : u1;
  const int      fc = owins ? oc : c1;
  const unsigned mx = owins ? am : om;
  unsigned s2 = (u2 & ~63u) < (o2 & ~63u) ? (u2 & ~63u) : (o2 & ~63u);
  s2 = s2 < mx ? s2 : mx;
  if (khalf == 0) {
    const bool nt = (__uint_as_float(s2) - __uint_as_float(f1 & ~63u)) < TAU;
    ((unsigned*)(ws + WS_RESW))[h * 65536 + tok] = f1;
    ((unsigned char*)(ws + WS_RESB))[h * 65536 + tok] =
        (unsigned char)(fc | (nt ? 0x80 : 0));   // fc in 0..31 (5 bits)
  }
}

// ---------------- Kernel M: 2-way merge + flags + loss (4 threads/token) -------
// 1024 blocks x 256 thr; token v = blk*64 + (tid>>2); channel slice (tid&3)*16.
__global__ __launch_bounds__(256) void k_merge(const float* __restrict__ emb,
    float* __restrict__ dout, char* __restrict__ ws)
{
  __shared__ float ls[4];
  const int tid = threadIdx.x;
  const int v = blockIdx.x * 64 + (tid >> 2);
  const int q4 = tid & 3;
  const unsigned* resw = (const unsigned*)(ws + WS_RESW);
  const unsigned char* resb = (const unsigned char*)(ws + WS_RESB);
  // winner merge (computed redundantly by all 4 threads of the quad)
  const unsigned A = resw[v], B = resw[65536 + v];
  const unsigned am = A & ~63u, bm = B & ~63u;
  const bool bwins = bm < am;
  const unsigned bw = bwins ? B : A;
  const int bq = bwins ? 1 : 0;
  const unsigned k1 = bwins ? bm : am;
  const unsigned k2 = bwins ? am : bm;
  const unsigned char bb = resb[bq * 65536 + v];
  const int code = bq * 2048 + (int)(bb & 31u) * 64 + (int)(bw & 63u);
  // loss slice: channels q4*16 .. q4*16+15
  const float* tcol = dout + v;
  const float* qe = emb + (size_t)code * 64 + q4 * 16;
  float acc = 0.f;
#pragma unroll
  for (int i = 0; i < 4; ++i) {
    const float4 qv = *(const float4*)(qe + i * 4);
#pragma unroll
    for (int j = 0; j < 4; ++j) {
      const int ch = q4 * 16 + i * 4 + j;
      const float d = tcol[(size_t)ch * NTOK] - ((const float*)&qv)[j];
      acc = fmaf(d, d, acc);
    }
  }
  acc += __shfl_xor(acc, 1);                   // quad-reduce: (p0+p1)+(p2+p3)
  acc += __shfl_xor(acc, 2);
  if (q4 == 0) {
    dout[OUT_ELEMS + 2 + v] = (float)code;
    const bool flag = (bb & 0x80u) ||
                      (__uint_as_float(k2) - __uint_as_float(k1) < TAU);
    if (flag) {
      int p = atomicAdd((int*)(ws + WS_CNT), 1);
      if (p < FLAG_CAP) ((int*)(ws + WS_FLAG))[p] = v;
    }
  }
  // block loss partial: every lane holds its token's full loss (x4 redundant);
  // xor-tree sum = 4 * sum(tokens) exactly -> scale by 0.25 (exact).
#pragma unroll
  for (int m = 4; m < 64; m <<= 1) acc += __shfl_xor(acc, m);
  const int lane = tid & 63, wv = tid >> 6;
  if (lane == 0) ls[wv] = acc;
  __syncthreads();
  if (tid == 0)
    ((float*)(ws + WS_PART))[blockIdx.x] = (ls[0] + ls[1] + ls[2] + ls[3]) * 0.25f;
}

// ---------------- Kernel R: f64 re-scan of near-tie tokens --------------------
// BLOCK-per-token (256 thr): thread scans 16 codes {tid, 256+tid, ...} with the
// proven per-code ACC4 f64 order. No in-loop barriers, no LDS tiles.
__global__ __launch_bounds__(256) void k_refine(const float* __restrict__ z,
    const float* __restrict__ emb, const float* __restrict__ pw, const float* __restrict__ pb,
    float* __restrict__ dout, char* __restrict__ ws)
{
  __shared__ double tdsh[64];
  __shared__ double dred[4]; __shared__ int kred[4];
  int cv = *(const int*)(ws + WS_CNT);
  if (cv > FLAG_CAP) cv = FLAG_CAP;
  const int slot = blockIdx.x;
  if (slot >= cv) return;
  const int tid = threadIdx.x;
  const int lane = tid & 63, wv = tid >> 6;
  const int n = ((const int*)(ws + WS_FLAG))[slot];

  if (tid < 64) {                                  // recompute token t in f64 (proven chain)
    const int b = n >> 15, r = n & (DHW - 1);
    const float* zp = z + (size_t)b * 64 * DHW + r;
    const float* wr = pw + tid * 64;
    double a = (double)pb[tid];
    for (int c2 = 0; c2 < 64; ++c2)
      a = fma((double)wr[c2], (double)zp[(size_t)c2 * DHW], a);
    tdsh[tid] = a;
  }
  __syncthreads();

  double td[64];                                   // all channels, static-indexed
#pragma unroll
  for (int j = 0; j < 64; ++j) td[j] = tdsh[j];    // broadcast reads

  double dmin = 1e300; int kmin = 0;
  for (int it = 0; it < 16; ++it) {
    const int code = it * 256 + tid;               // ascending per thread
    const float4* e = (const float4*)(emb + (size_t)code * 64);
    double d0 = 0.0, d1 = 0.0;
#pragma unroll
    for (int i = 0; i < 16; ++i) {
      const float4 ev = e[i];
      const double x0 = td[4 * i]     - (double)ev.x; d0 = fma(x0, x0, d0);
      const double x1 = td[4 * i + 1] - (double)ev.y; d1 = fma(x1, x1, d1);
      const double x2 = td[4 * i + 2] - (double)ev.z; d0 = fma(x2, x2, d0);
      const double x3 = td[4 * i + 3] - (double)ev.w; d1 = fma(x3, x3, d1);
    }
    const double d = d0 + d1;
    if (d < dmin) { dmin = d; kmin = code; }       // strict < -> lowest code kept
  }
#pragma unroll
  for (int m = 1; m < 64; m <<= 1) {               // wave argmin, lower-code tiebreak
    const double od = __shfl_xor(dmin, m);
    const int    ok = __shfl_xor(kmin, m);
    if (od < dmin || (od == dmin && ok < kmin)) { dmin = od; kmin = ok; }
  }
  if (lane == 0) { dred[wv] = dmin; kred[wv] = kmin; }
  __syncthreads();
  if (tid == 0) {
#pragma unroll
    for (int i = 1; i < 4; ++i)
      if (dred[i] < dmin || (dred[i] == dmin && kred[i] < kmin)) { dmin = dred[i]; kmin = kred[i]; }
    dout[OUT_ELEMS + 2 + n] = (float)kmin;
  }
}

// ---------------- Kernel D: post-conv (out = post_w@q + post_b) + loss final ---
__global__ __launch_bounds__(256) void k_post(const float* __restrict__ emb,
    const float* __restrict__ ow, const float* __restrict__ ob,
    float* __restrict__ dout, const char* __restrict__ ws)
{
  __shared__ float ps[256];
  const int v = blockIdx.x * 256 + threadIdx.x;
  const int b = v >> 15, r = v & (DHW - 1);
  const int code = (int)dout[OUT_ELEMS + 2 + v];
  const float* q = emb + (size_t)code * 64;
  float qr[64];
#pragma unroll
  for (int i = 0; i < 16; ++i) *(float4*)(qr + i * 4) = *(const float4*)(q + i * 4);
  float* op = dout + (size_t)b * 64 * DHW + r;
  for (int o = 0; o < 64; o += 4) {           // 4 independent chains (ILP)
    const float* w0 = ow + o * 64;
    const float* w1 = ow + (o + 1) * 64;
    const float* w2 = ow + (o + 2) * 64;
    const float* w3 = ow + (o + 3) * 64;
    float a0 = ob[o], a1 = ob[o + 1], a2 = ob[o + 2], a3 = ob[o + 3];
#pragma unroll
    for (int cch = 0; cch < 64; ++cch) {      // per-channel order unchanged
      const float qv = qr[cch];
      a0 = fmaf(w0[cch], qv, a0); a1 = fmaf(w1[cch], qv, a1);
      a2 = fmaf(w2[cch], qv, a2); a3 = fmaf(w3[cch], qv, a3);
    }
    op[(size_t)o * DHW]       = a0;
    op[(size_t)(o + 1) * DHW] = a1;
    op[(size_t)(o + 2) * DHW] = a2;
    op[(size_t)(o + 3) * DHW] = a3;
  }
  if (blockIdx.x == 0) {
    const float* part = (const float*)(ws + WS_PART);
    const int t4 = threadIdx.x * 4;
    float s = ((part[t4] + part[t4 + 1]) + part[t4 + 2]) + part[t4 + 3];
    ps[threadIdx.x] = s;
    __syncthreads();
    if (threadIdx.x == 0) {
      float tot = 0.f;
      for (int i = 0; i < 256; ++i) tot += ps[i];   // fixed order: deterministic
      const float mean = tot / 4194304.0f;
      dout[OUT_ELEMS]     = mean;   // codebook_loss
      dout[OUT_ELEMS + 1] = mean;   // commitment_loss
    }
  }
}

extern "C" void kernel_launch(void* const* d_in, const int* in_sizes, int n_in,
                              void* d_out, int out_size, void* d_ws, size_t ws_size,
                              hipStream_t stream) {
  (void)in_sizes; (void)n_in; (void)out_size; (void)ws_size;
  const float* z   = (const float*)d_in[0];
  const float* emb = (const float*)d_in[1];
  const float* pw  = (const float*)d_in[2];
  const float* pb  = (const float*)d_in[3];
  const float* ow  = (const float*)d_in[4];
  const float* ob  = (const float*)d_in[5];
  float* out = (float*)d_out;
  char*  ws  = (char*)d_ws;

  hipLaunchKernelGGL(k_pre,    dim3(320),  dim3(256), 0, stream, z, emb, pw, pb, out, ws);
  hipLaunchKernelGGL(k_dist,   dim3(512),  dim3(512), 0, stream, out, ws);
  hipLaunchKernelGGL(k_merge,  dim3(1024), dim3(256), 0, stream, emb, out, ws);
  hipLaunchKernelGGL(k_refine, dim3(FLAG_CAP), dim3(256), 0, stream, z, emb, pw, pb, out, ws);
  hipLaunchKernelGGL(k_post,   dim3(256),  dim3(256), 0, stream, emb, ow, ob, out, ws);
}

// Round 9
// 194.784 us; speedup vs baseline: 1.7915x; 1.0094x over previous
//
#include <hip/hip_runtime.h>
#include <cstdint>
#include <cstddef>

typedef float  f32x4  __attribute__((ext_vector_type(4)));
typedef float  f32x16 __attribute__((ext_vector_type(16)));
typedef short  s16x8  __attribute__((ext_vector_type(8)));

#define DEV __device__ __forceinline__

static constexpr int    DHW       = 32768;       // 8*64*64
static constexpr int    NTOK      = 65536;       // B*D*H*W
static constexpr int    CHUNK_B   = 18432;       // 16384 gh/gl + 1KB e2 + zero slot + pad
static constexpr size_t OUT_ELEMS = 4194304;     // 2*64*32768
static constexpr float  BIGC      = 512.0f;      // positivity bias for uint-compare
static constexpr float  TAU       = 0.015f;      // near-tie refinement threshold
static constexpr int    FLAG_CAP  = 7424;        // sized so ws end == 2,524,416 (proven)

// workspace layout (end = 2,524,416 B)
static constexpr size_t WS_PREP = 0;             // 64*18432 = 1,179,648
static constexpr size_t WS_RESW = 1179648;       // 2*65536*4 (per-half winner word)
static constexpr size_t WS_RESB = 2228224;       // 2*65536*1 (chunk | tie-bit)
static constexpr size_t WS_PART = 2490368;       // 1024*4
static constexpr size_t WS_CNT  = 2494464;       // int
static constexpr size_t WS_FLAG = 2494720;       // FLAG_CAP*4 -> end 2,524,416

DEV unsigned f2bf(float f) {            // RNE float -> bf16 bits
  unsigned u = __float_as_uint(f);
  return (u + 0x7FFFu + ((u >> 16) & 1u)) >> 16;
}
DEV float bf2f(unsigned h) { return __uint_as_float(h << 16); }
DEV unsigned med3u(unsigned a, unsigned b, unsigned c) {
  unsigned r;
  asm("v_med3_u32 %0, %1, %2, %3" : "=v"(r) : "v"(a), "v"(b), "v"(c));
  return r;
}
DEV void gl_lds16(const void* g, void* l) {   // 64 lanes x 16B, dest = base + lane*16
  __builtin_amdgcn_global_load_lds(
      (const __attribute__((address_space(1))) unsigned int*)g,
      (__attribute__((address_space(3))) unsigned int*)l, 16, 0, 0);
}

// ---------------- Kernel A: pre-conv (t = pre_w@z + pre_b) + embedding prep ----
// t stored [C=64][NTOK] inside d_out (overwritten later by k_post).
__global__ __launch_bounds__(256) void k_pre(const float* __restrict__ z,
    const float* __restrict__ emb, const float* __restrict__ pw, const float* __restrict__ pb,
    float* __restrict__ dout, char* __restrict__ ws)
{
  const int blk = blockIdx.x, tid = threadIdx.x;
  if (blk == 0 && tid == 0) *(int*)(ws + WS_CNT) = 0;
  if (blk < 256) {
    float* t = dout;
    const int v = blk * 256 + tid;
    const int b = v >> 15, r = v & (DHW - 1);
    const float* zp = z + (size_t)b * 64 * DHW + r;
    float zr[64];
#pragma unroll
    for (int c2 = 0; c2 < 64; ++c2) zr[c2] = zp[(size_t)c2 * DHW];
    for (int c = 0; c < 64; c += 4) {        // 4 independent chains (ILP)
      const float* w0 = pw + c * 64;
      const float* w1 = pw + (c + 1) * 64;
      const float* w2 = pw + (c + 2) * 64;
      const float* w3 = pw + (c + 3) * 64;
      float a0 = pb[c], a1 = pb[c + 1], a2 = pb[c + 2], a3 = pb[c + 3];
#pragma unroll
      for (int c2 = 0; c2 < 64; ++c2) {      // per-channel order unchanged
        const float zv = zr[c2];
        a0 = fmaf(w0[c2], zv, a0); a1 = fmaf(w1[c2], zv, a1);
        a2 = fmaf(w2[c2], zv, a2); a3 = fmaf(w3[c2], zv, a3);
      }
      t[(size_t)c * NTOK + v]       = a0;
      t[(size_t)(c + 1) * NTOK + v] = a1;
      t[(size_t)(c + 2) * NTOK + v] = a2;
      t[(size_t)(c + 3) * NTOK + v] = a3;
    }
  } else {
    const int tt = (blk - 256) * 256 + tid;  // 0..16383, 2 units each
#pragma unroll
    for (int uu = 0; uu < 2; ++uu) {
      const int u = tt * 2 + uu;
      const int k = u >> 3, j = u & 7;       // code k, 8-channel group j
      const float* ep = emb + (size_t)k * 64 + j * 8;
      unsigned hw[4], lw[4];
#pragma unroll
      for (int i = 0; i < 4; ++i) {
        float g0 = -2.0f * ep[2 * i], g1 = -2.0f * ep[2 * i + 1];
        unsigned h0 = f2bf(g0); unsigned l0 = f2bf(g0 - bf2f(h0));
        unsigned h1 = f2bf(g1); unsigned l1 = f2bf(g1 - bf2f(h1));
        hw[i] = h0 | (h1 << 16); lw[i] = l0 | (l1 << 16);
      }
      char* base = ws + WS_PREP + (size_t)(k >> 6) * CHUNK_B;
      const int r = k & 63;
      const int swz = (r & 15) << 4;
      char* rowp = base + r * 256;
      *(uint4*)(rowp + ((j * 16) ^ swz))        = make_uint4(hw[0], hw[1], hw[2], hw[3]);
      *(uint4*)(rowp + ((128 + j * 16) ^ swz))  = make_uint4(lw[0], lw[1], lw[2], lw[3]);
      if (j == 0) {
        const float* er = emb + (size_t)k * 64;
        float s = 0.f;
#pragma unroll
        for (int c = 0; c < 64; ++c) s = fmaf(er[c], er[c], s);
        s += BIGC;
        unsigned eh  = f2bf(s);
        float    rs  = s - bf2f(eh);
        unsigned el  = f2bf(rs);
        unsigned el2 = f2bf(rs - bf2f(el));
        *(uint4*)(base + 16384 + r * 16) = make_uint4(eh | (el << 16), el2, 0u, 0u);
        if (r == 0) *(uint4*)(base + 16384 + 1024) = make_uint4(0u, 0u, 0u, 0u);
      }
    }
  }
}

// ---------------- Kernel B: bf16x3 MFMA distance (32x32x16) -------------------
// Wave-pair row split: wave handles 64 tokens x 32 code-rows (parity p of its
// pair). Halves LDS reads per MFMA (18KB->9KB per 26 MFMAs) vs the 32x64
// layout — k_dist was LDS-BW-bound (708 B/MFMA at the 85B/cy ceiling).
// grid = 512 blocks x 512 thr: tokens (bid>>1)*256..+256 (pair = 64 tokens),
// chunks (bid&1)*32..+32. Final pair merge via LDS exchange (exact top-2).
__global__ __launch_bounds__(512, 4) void k_dist(float* __restrict__ dout,
                                                 char* __restrict__ ws)
{
  constexpr int NCH = 32;
  __shared__ __align__(16) char smem[2 * CHUNK_B];
  __shared__ unsigned xch[4][64][3];           // odd->even pair exchange
  const float* t = dout;                       // [64][NTOK]
  const int tid = threadIdx.x;
  const int w = tid >> 6, lane = tid & 63;
  const int l31 = lane & 31, khalf = lane >> 5;
  const int pair = w >> 1, p = w & 1;
  const int gidx = blockIdx.x >> 1, h = blockIdx.x & 1;
  const int tb = gidx * 256 + pair * 64;

  // ---- B-fragments: 2 token groups (tf), t[k][tok], k = kt*16 + khalf*8 + i --
  s16x8 tav[2][4], tlv[2][4];
#pragma unroll
  for (int tf = 0; tf < 2; ++tf) {
#pragma unroll
    for (int kt = 0; kt < 4; ++kt) {
      const float* tc = t + (size_t)(kt * 16 + khalf * 8) * NTOK + (tb + tf * 32 + l31);
      float f[8];
#pragma unroll
      for (int i = 0; i < 8; ++i) f[i] = tc[(size_t)i * NTOK];
      union { unsigned u[4]; s16x8 v; } xh, xl;
#pragma unroll
      for (int i = 0; i < 4; ++i) {
        unsigned h0 = f2bf(f[2 * i]),     l0 = f2bf(f[2 * i]     - bf2f(h0));
        unsigned h1 = f2bf(f[2 * i + 1]), l1 = f2bf(f[2 * i + 1] - bf2f(h1));
        xh.u[i] = h0 | (h1 << 16); xl.u[i] = l0 | (l1 << 16);
      }
      tav[tf][kt] = xh.v; tlv[tf][kt] = xl.v;
    }
  }
  s16x8 ones;                                  // B for e2-MFMA: k'=0,1,2 -> 1.0 (khalf 0)
  { union { unsigned u[4]; s16x8 v; } o;
    o.u[0] = khalf ? 0u : 0x3F803F80u;
    o.u[1] = khalf ? 0u : 0x00003F80u;
    o.u[2] = 0u; o.u[3] = 0u; ones = o.v; }

  const char* prep = ws + WS_PREP + (size_t)h * NCH * CHUNK_B;
  const int swz  = (l31 & 15) << 4;
  const int rowb = (p * 32 + l31) * 256;       // this wave's code-row in chunk
  const int eoff = khalf ? (16384 + 1024) : (16384 + (p * 32 + l31) * 16);

  // prologue: stage chunk 0 (linear copy: prep is pre-swizzled)
  {
    const char* src = prep;
    gl_lds16(src + w * 1024 + lane * 16, smem + w * 1024);
    gl_lds16(src + 8192 + w * 1024 + lane * 16, smem + 8192 + w * 1024);
    if (w < 2) gl_lds16(src + 16384 + w * 1024 + lane * 16, smem + 16384 + w * 1024);
  }
  __syncthreads();

  unsigned u1[2] = {0x7f800000u, 0x7f800000u};
  unsigned u2[2] = {0x7f800000u, 0x7f800000u};
  int c1[2] = {0, 0};

  for (int c = 0; c < NCH; ++c) {
    const char* L = smem + (c & 1) * CHUNK_B;
    if (c + 1 < NCH) {                         // issue next-chunk stage early
      const char* src = prep + (size_t)(c + 1) * CHUNK_B;
      char* dst = smem + ((c + 1) & 1) * CHUNK_B;
      gl_lds16(src + w * 1024 + lane * 16, dst + w * 1024);
      gl_lds16(src + 8192 + w * 1024 + lane * 16, dst + 8192 + w * 1024);
      if (w < 2) gl_lds16(src + 16384 + w * 1024 + lane * 16, dst + 16384 + w * 1024);
    }
    f32x16 acc0 = {}, acc1 = {};
    {                                          // e2 seed via MFMA (adds 512+||e||^2)
      const s16x8 e0 = *(const s16x8*)(L + eoff);
      acc0 = __builtin_amdgcn_mfma_f32_32x32x16_bf16(e0, ones, acc0, 0, 0, 0);
      acc1 = __builtin_amdgcn_mfma_f32_32x32x16_bf16(e0, ones, acc1, 0, 0, 0);
    }
#pragma unroll
    for (int kt = 0; kt < 4; ++kt) {           // one row-tile, reused by both tf
      const int i0 = (kt * 32 + khalf * 16) ^ swz;
      const s16x8 gh = *(const s16x8*)(L + rowb + i0);
      const s16x8 gl = *(const s16x8*)(L + rowb + (i0 ^ 128));
      acc0 = __builtin_amdgcn_mfma_f32_32x32x16_bf16(gh, tav[0][kt], acc0, 0, 0, 0);
      acc0 = __builtin_amdgcn_mfma_f32_32x32x16_bf16(gh, tlv[0][kt], acc0, 0, 0, 0);
      acc0 = __builtin_amdgcn_mfma_f32_32x32x16_bf16(gl, tav[0][kt], acc0, 0, 0, 0);
      acc1 = __builtin_amdgcn_mfma_f32_32x32x16_bf16(gh, tav[1][kt], acc1, 0, 0, 0);
      acc1 = __builtin_amdgcn_mfma_f32_32x32x16_bf16(gh, tlv[1][kt], acc1, 0, 0, 0);
      acc1 = __builtin_amdgcn_mfma_f32_32x32x16_bf16(gl, tav[1][kt], acc1, 0, 0, 0);
    }
    // argmin keys: local row = (q&3)+8*(q>>2) (+4*khalf, +32*p OR'd at end)
    const unsigned pa = u1[0], pb2 = u1[1];
#pragma unroll
    for (int q = 0; q < 16; ++q) {
      const unsigned w0 = (unsigned)((q & 3) + 8 * (q >> 2));
      unsigned v0 = (__float_as_uint(acc0[q]) & ~63u) | w0;
      u2[0] = med3u(u1[0], v0, u2[0]); u1[0] = u1[0] < v0 ? u1[0] : v0;
      unsigned v1 = (__float_as_uint(acc1[q]) & ~63u) | w0;
      u2[1] = med3u(u1[1], v1, u2[1]); u1[1] = u1[1] < v1 ? u1[1] : v1;
    }
    if (u1[0] != pa)  c1[0] = c;
    if (u1[1] != pb2) c1[1] = c;
    __syncthreads();                           // drains vmcnt -> next chunk staged
  }

  // complete wid (khalf bit 2, pair-parity bit 5), then khalf merge per tf
  const unsigned addb = (unsigned)(khalf * 4 + p * 32);
  unsigned rf1[2], rs2[2]; int rfc[2];
#pragma unroll
  for (int tf = 0; tf < 2; ++tf) {
    unsigned a1 = u1[tf] | addb;
    unsigned a2 = u2[tf];
    int cc = c1[tf];
    const unsigned o1 = __shfl_xor(a1, 32);
    const unsigned o2 = __shfl_xor(a2, 32);
    const int      oc = __shfl_xor(cc, 32);
    const unsigned am = a1 & ~63u, om = o1 & ~63u;
    const int mycode = cc * 64 + (int)(a1 & 63u);
    const int ocode  = oc * 64 + (int)(o1 & 63u);
    const bool ow = (om < am) || (om == am && ocode < mycode);
    rf1[tf] = ow ? o1 : a1;
    rfc[tf] = ow ? oc : cc;
    const unsigned mx = ow ? am : om;
    unsigned s2 = (a2 & ~63u) < (o2 & ~63u) ? (a2 & ~63u) : (o2 & ~63u);
    rs2[tf] = s2 < mx ? s2 : mx;
  }
  if (p == 1 && khalf == 0) {                  // odd wave publishes its row-half
#pragma unroll
    for (int tf = 0; tf < 2; ++tf) {
      xch[pair][tf * 32 + l31][0] = rf1[tf];
      xch[pair][tf * 32 + l31][1] = rs2[tf];
      xch[pair][tf * 32 + l31][2] = (unsigned)rfc[tf];
    }
  }
  __syncthreads();
  if (p == 0 && khalf == 0) {                  // even wave merges + writes
#pragma unroll
    for (int tf = 0; tf < 2; ++tf) {
      const unsigned of1 = xch[pair][tf * 32 + l31][0];
      const unsigned os2 = xch[pair][tf * 32 + l31][1];
      const int      ofc = (int)xch[pair][tf * 32 + l31][2];
      const unsigned am = rf1[tf] & ~63u, om = of1 & ~63u;
      const int mycode = rfc[tf] * 64 + (int)(rf1[tf] & 63u);
      const int ocode  = ofc * 64 + (int)(of1 & 63u);
      const bool ow = (om < am) || (om == am && ocode < mycode);
      const unsigned F1 = ow ? of1 : rf1[tf];
      const int      FC = ow ? ofc : rfc[tf];
      const unsigned mx = ow ? am : om;
      unsigned S2 = rs2[tf] < os2 ? rs2[tf] : os2;   // both already masked
      S2 = S2 < mx ? S2 : mx;
      const bool nt = (__uint_as_float(S2) - __uint_as_float(F1 & ~63u)) < TAU;
      const int tok = tb + tf * 32 + l31;
      ((unsigned*)(ws + WS_RESW))[h * 65536 + tok] = F1;
      ((unsigned char*)(ws + WS_RESB))[h * 65536 + tok] =
          (unsigned char)(FC | (nt ? 0x80 : 0));     // FC in 0..31 (5 bits)
    }
  }
}

// ---------------- Kernel M: 2-way merge + flags + loss (4 threads/token) -------
// 1024 blocks x 256 thr; token v = blk*64 + (tid>>2); channel slice (tid&3)*16.
__global__ __launch_bounds__(256) void k_merge(const float* __restrict__ emb,
    float* __restrict__ dout, char* __restrict__ ws)
{
  __shared__ float ls[4];
  const int tid = threadIdx.x;
  const int v = blockIdx.x * 64 + (tid >> 2);
  const int q4 = tid & 3;
  const unsigned* resw = (const unsigned*)(ws + WS_RESW);
  const unsigned char* resb = (const unsigned char*)(ws + WS_RESB);
  // winner merge (computed redundantly by all 4 threads of the quad)
  const unsigned A = resw[v], B = resw[65536 + v];
  const unsigned am = A & ~63u, bm = B & ~63u;
  const bool bwins = bm < am;
  const unsigned bw = bwins ? B : A;
  const int bq = bwins ? 1 : 0;
  const unsigned k1 = bwins ? bm : am;
  const unsigned k2 = bwins ? am : bm;
  const unsigned char bb = resb[bq * 65536 + v];
  const int code = bq * 2048 + (int)(bb & 31u) * 64 + (int)(bw & 63u);
  // loss slice: channels q4*16 .. q4*16+15
  const float* tcol = dout + v;
  const float* qe = emb + (size_t)code * 64 + q4 * 16;
  float acc = 0.f;
#pragma unroll
  for (int i = 0; i < 4; ++i) {
    const float4 qv = *(const float4*)(qe + i * 4);
#pragma unroll
    for (int j = 0; j < 4; ++j) {
      const int ch = q4 * 16 + i * 4 + j;
      const float d = tcol[(size_t)ch * NTOK] - ((const float*)&qv)[j];
      acc = fmaf(d, d, acc);
    }
  }
  acc += __shfl_xor(acc, 1);                   // quad-reduce: full token loss/lane
  acc += __shfl_xor(acc, 2);
  if (q4 == 0) {
    dout[OUT_ELEMS + 2 + v] = (float)code;
    const bool flag = (bb & 0x80u) ||
                      (__uint_as_float(k2) - __uint_as_float(k1) < TAU);
    if (flag) {
      int p = atomicAdd((int*)(ws + WS_CNT), 1);
      if (p < FLAG_CAP) ((int*)(ws + WS_FLAG))[p] = v;
    }
  }
  // tree over masks 4..32 sums each token ONCE per lane-residue (r8's *0.25 was
  // a 4x-undercount bug: error == 3/4 * loss_ref == 0.8027, observed exactly).
#pragma unroll
  for (int m = 4; m < 64; m <<= 1) acc += __shfl_xor(acc, m);
  const int lane = tid & 63, wv = tid >> 6;
  if (lane == 0) ls[wv] = acc;
  __syncthreads();
  if (tid == 0)
    ((float*)(ws + WS_PART))[blockIdx.x] = ls[0] + ls[1] + ls[2] + ls[3];
}

// ---------------- Kernel R: f64 re-scan of near-tie tokens --------------------
// BLOCK-per-token (256 thr): thread scans 16 codes {tid, 256+tid, ...} with the
// proven per-code ACC4 f64 order. No in-loop barriers, no LDS tiles.
__global__ __launch_bounds__(256) void k_refine(const float* __restrict__ z,
    const float* __restrict__ emb, const float* __restrict__ pw, const float* __restrict__ pb,
    float* __restrict__ dout, char* __restrict__ ws)
{
  __shared__ double tdsh[64];
  __shared__ double dred[4]; __shared__ int kred[4];
  int cv = *(const int*)(ws + WS_CNT);
  if (cv > FLAG_CAP) cv = FLAG_CAP;
  const int slot = blockIdx.x;
  if (slot >= cv) return;
  const int tid = threadIdx.x;
  const int lane = tid & 63, wv = tid >> 6;
  const int n = ((const int*)(ws + WS_FLAG))[slot];

  if (tid < 64) {                                  // recompute token t in f64 (proven chain)
    const int b = n >> 15, r = n & (DHW - 1);
    const float* zp = z + (size_t)b * 64 * DHW + r;
    const float* wr = pw + tid * 64;
    double a = (double)pb[tid];
    for (int c2 = 0; c2 < 64; ++c2)
      a = fma((double)wr[c2], (double)zp[(size_t)c2 * DHW], a);
    tdsh[tid] = a;
  }
  __syncthreads();

  double td[64];                                   // all channels, static-indexed
#pragma unroll
  for (int j = 0; j < 64; ++j) td[j] = tdsh[j];    // broadcast reads

  double dmin = 1e300; int kmin = 0;
  for (int it = 0; it < 16; ++it) {
    const int code = it * 256 + tid;               // ascending per thread
    const float4* e = (const float4*)(emb + (size_t)code * 64);
    double d0 = 0.0, d1 = 0.0;
#pragma unroll
    for (int i = 0; i < 16; ++i) {
      const float4 ev = e[i];
      const double x0 = td[4 * i]     - (double)ev.x; d0 = fma(x0, x0, d0);
      const double x1 = td[4 * i + 1] - (double)ev.y; d1 = fma(x1, x1, d1);
      const double x2 = td[4 * i + 2] - (double)ev.z; d0 = fma(x2, x2, d0);
      const double x3 = td[4 * i + 3] - (double)ev.w; d1 = fma(x3, x3, d1);
    }
    const double d = d0 + d1;
    if (d < dmin) { dmin = d; kmin = code; }       // strict < -> lowest code kept
  }
#pragma unroll
  for (int m = 1; m < 64; m <<= 1) {               // wave argmin, lower-code tiebreak
    const double od = __shfl_xor(dmin, m);
    const int    ok = __shfl_xor(kmin, m);
    if (od < dmin || (od == dmin && ok < kmin)) { dmin = od; kmin = ok; }
  }
  if (lane == 0) { dred[wv] = dmin; kred[wv] = kmin; }
  __syncthreads();
  if (tid == 0) {
#pragma unroll
    for (int i = 1; i < 4; ++i)
      if (dred[i] < dmin || (dred[i] == dmin && kred[i] < kmin)) { dmin = dred[i]; kmin = kred[i]; }
    dout[OUT_ELEMS + 2 + n] = (float)kmin;
  }
}

// ---------------- Kernel D: post-conv (out = post_w@q + post_b) + loss final ---
__global__ __launch_bounds__(256) void k_post(const float* __restrict__ emb,
    const float* __restrict__ ow, const float* __restrict__ ob,
    float* __restrict__ dout, const char* __restrict__ ws)
{
  __shared__ float ps[256];
  const int v = blockIdx.x * 256 + threadIdx.x;
  const int b = v >> 15, r = v & (DHW - 1);
  const int code = (int)dout[OUT_ELEMS + 2 + v];
  const float* q = emb + (size_t)code * 64;
  float qr[64];
#pragma unroll
  for (int i = 0; i < 16; ++i) *(float4*)(qr + i * 4) = *(const float4*)(q + i * 4);
  float* op = dout + (size_t)b * 64 * DHW + r;
  for (int o = 0; o < 64; o += 4) {           // 4 independent chains (ILP)
    const float* w0 = ow + o * 64;
    const float* w1 = ow + (o + 1) * 64;
    const float* w2 = ow + (o + 2) * 64;
    const float* w3 = ow + (o + 3) * 64;
    float a0 = ob[o], a1 = ob[o + 1], a2 = ob[o + 2], a3 = ob[o + 3];
#pragma unroll
    for (int cch = 0; cch < 64; ++cch) {      // per-channel order unchanged
      const float qv = qr[cch];
      a0 = fmaf(w0[cch], qv, a0); a1 = fmaf(w1[cch], qv, a1);
      a2 = fmaf(w2[cch], qv, a2); a3 = fmaf(w3[cch], qv, a3);
    }
    op[(size_t)o * DHW]       = a0;
    op[(size_t)(o + 1) * DHW] = a1;
    op[(size_t)(o + 2) * DHW] = a2;
    op[(size_t)(o + 3) * DHW] = a3;
  }
  if (blockIdx.x == 0) {
    const float* part = (const float*)(ws + WS_PART);
    const int t4 = threadIdx.x * 4;
    float s = ((part[t4] + part[t4 + 1]) + part[t4 + 2]) + part[t4 + 3];
    ps[threadIdx.x] = s;
    __syncthreads();
    if (threadIdx.x == 0) {
      float tot = 0.f;
      for (int i = 0; i < 256; ++i) tot += ps[i];   // fixed order: deterministic
      const float mean = tot / 4194304.0f;
      dout[OUT_ELEMS]     = mean;   // codebook_loss
      dout[OUT_ELEMS + 1] = mean;   // commitment_loss
    }
  }
}

extern "C" void kernel_launch(void* const* d_in, const int* in_sizes, int n_in,
                              void* d_out, int out_size, void* d_ws, size_t ws_size,
                              hipStream_t stream) {
  (void)in_sizes; (void)n_in; (void)out_size; (void)ws_size;
  const float* z   = (const float*)d_in[0];
  const float* emb = (const float*)d_in[1];
  const float* pw  = (const float*)d_in[2];
  const float* pb  = (const float*)d_in[3];
  const float* ow  = (const float*)d_in[4];
  const float* ob  = (const float*)d_in[5];
  float* out = (float*)d_out;
  char*  ws  = (char*)d_ws;

  hipLaunchKernelGGL(k_pre,    dim3(320),  dim3(256), 0, stream, z, emb, pw, pb, out, ws);
  hipLaunchKernelGGL(k_dist,   dim3(512),  dim3(512), 0, stream, out, ws);
  hipLaunchKernelGGL(k_merge,  dim3(1024), dim3(256), 0, stream, emb, out, ws);
  hipLaunchKernelGGL(k_refine, dim3(FLAG_CAP), dim3(256), 0, stream, z, emb, pw, pb, out, ws);
  hipLaunchKernelGGL(k_post,   dim3(256),  dim3(256), 0, stream, emb, ow, ob, out, ws);
}